// Round 2
// baseline (22017.567 us; speedup 1.0000x reference)
//
#include <hip/hip_runtime.h>
#include <hip/hip_cooperative_groups.h>
#include <math.h>

namespace cg = cooperative_groups;

// ---------------------------------------------------------------------------
// Pointer-network decoder, 50 sequential greedy-decode steps.
// R5: persistent cooperative kernel for the whole decode loop (3 grid.sync
// per step), c-state in registers, mask in LDS. Fallback to the R4 dispatch
// loop if cooperative launch is rejected. mfma_gemm bf16 epilogue now stages
// through LDS and stores coalesced uint4 (fixes measured 8x write-amp on pa).
// ---------------------------------------------------------------------------

#define S_LEN 50
#define BATCH 512
#define HDIM  512
#define H4    2048
#define BH    (BATCH*HDIM)          // 262144
#define BS    (BATCH*S_LEN)         // 25600
#define KSPQ  4
#define MASK50 0x0003FFFFFFFFFFFFULL

typedef unsigned short u16;
typedef __attribute__((ext_vector_type(8))) short bf16x8;
typedef __attribute__((ext_vector_type(4))) float f32x4;

__device__ __forceinline__ float wave_sum(float v){
  #pragma unroll
  for (int o=32;o;o>>=1) v += __shfl_xor(v,o);
  return v;
}
__device__ __forceinline__ float wave_max(float v){
  #pragma unroll
  for (int o=32;o;o>>=1) v = fmaxf(v,__shfl_xor(v,o));
  return v;
}
__device__ __forceinline__ float sigmoidf_(float x){ return 1.0f/(1.0f+expf(-x)); }
__device__ __forceinline__ u16 f2b(float f){
  unsigned u = __float_as_uint(f);
  unsigned r = (u + 0x7fffu + ((u>>16)&1u)) >> 16;
  return (u16)r;
}
__device__ __forceinline__ float b2f(u16 h){ return __uint_as_float(((unsigned)h)<<16); }

// ---------------------------------------------------------------------------
// Generic bf16 MFMA GEMM (prologue + fallback). 128x128 tile, BK=64.
// bf16 output path: LDS-staged, coalesced uint4 stores (write-amp fix).
// ---------------------------------------------------------------------------
struct MArgs {
  const u16* A[4]; const u16* W[4]; const float* bias[4]; void* C[4];
  int M, N, K, lda, ksplit, out_bf16;
};

__global__ __launch_bounds__(256, 2) void mfma_gemm(MArgs g) {
  const int z = blockIdx.z;
  const u16* __restrict__ A = g.A[z];
  const u16* __restrict__ W = g.W[z];
  const float* __restrict__ bias = g.bias[z];
  const int N = g.N, K = g.K, lda = g.lda;
  const int mtile = blockIdx.y / g.ksplit;
  const int ksp   = blockIdx.y % g.ksplit;
  const int m0 = mtile*128, n0 = blockIdx.x*128;
  const int kc = K / g.ksplit;
  const int kbeg = ksp*kc, kend = kbeg+kc;

  __shared__ __align__(16) u16 sh[2*128*88];
  u16* As = sh;
  u16* Bs = sh + 128*88;

  const int tid = threadIdx.x;
  const int wave = tid>>6, lane = tid&63;
  const int wm = (wave>>1)*64, wn = (wave&1)*64;
  const int m16 = lane&15, quad = lane>>4;

  f32x4 acc[4][4];
  #pragma unroll
  for (int i=0;i<4;i++)
    #pragma unroll
    for (int j=0;j<4;j++) acc[i][j] = (f32x4){0.f,0.f,0.f,0.f};

  for (int kt = kbeg; kt < kend; kt += 64) {
    uint4 av[4], wv[4];
    #pragma unroll
    for (int it=0; it<4; it++){
      int idx = tid + it*256;
      int r = idx>>3, c = idx&7;
      av[it] = *(const uint4*)(A + (size_t)(m0+r)*lda + kt + c*8);
      wv[it] = *(const uint4*)(W + (size_t)(n0+r)*K + kt + c*8);
    }
    __syncthreads();
    #pragma unroll
    for (int it=0; it<4; it++){
      int idx = tid + it*256;
      int r = idx>>3, c = idx&7;
      *(uint4*)&As[r*88 + c*8] = av[it];
      *(uint4*)&Bs[r*88 + c*8] = wv[it];
    }
    __syncthreads();
    #pragma unroll
    for (int ks=0; ks<2; ks++){
      bf16x8 af[4], bfr[4];
      #pragma unroll
      for (int i=0;i<4;i++) af[i] = *(const bf16x8*)&As[(wm + i*16 + m16)*88 + ks*32 + quad*8];
      #pragma unroll
      for (int j=0;j<4;j++) bfr[j] = *(const bf16x8*)&Bs[(wn + j*16 + m16)*88 + ks*32 + quad*8];
      #pragma unroll
      for (int i=0;i<4;i++)
        #pragma unroll
        for (int j=0;j<4;j++)
          acc[i][j] = __builtin_amdgcn_mfma_f32_16x16x32_bf16(af[i], bfr[j], acc[i][j], 0, 0, 0);
    }
  }

  if (g.out_bf16) {
    // stage bf16 tile (bias added) in LDS, then write coalesced uint4 rows
    u16* C = (u16*)g.C[z];
    __syncthreads();
    #pragma unroll
    for (int i=0;i<4;i++){
      #pragma unroll
      for (int j=0;j<4;j++){
        int cc = wn + j*16 + m16;
        float bv = bias ? bias[n0 + cc] : 0.0f;
        #pragma unroll
        for (int r=0;r<4;r++)
          sh[(wm + i*16 + quad*4 + r)*128 + cc] = f2b(acc[i][j][r] + bv);
      }
    }
    __syncthreads();
    #pragma unroll
    for (int k=0;k<8;k++){
      int idx = tid + k*256;
      int row = idx>>4, c = idx&15;
      *(uint4*)(C + (size_t)(m0+row)*N + n0 + c*8) = *(const uint4*)&sh[row*128 + c*8];
    }
  } else {
    float* C = (float*)g.C[z] + (size_t)ksp*g.M*N;
    #pragma unroll
    for (int i=0;i<4;i++){
      int mb = m0 + wm + i*16 + quad*4;
      #pragma unroll
      for (int j=0;j<4;j++){
        int n = n0 + wn + j*16 + m16;
        float bv = bias ? bias[n] : 0.0f;
        #pragma unroll
        for (int r=0;r<4;r++)
          C[(size_t)(mb+r)*N + n] = acc[i][j][r] + bv;
      }
    }
  }
}

// ---------------------------------------------------------------------------
// Fallback LSTM GEMM (R4): concat-K [x|h], gate-interleaved Wc, fused gates.
// ---------------------------------------------------------------------------
__global__ __launch_bounds__(256, 2) void lstm_gemm(
    const u16* __restrict__ xh_cur, u16* __restrict__ xh_nxt,
    const u16* __restrict__ Wc, const float* __restrict__ bc,
    float* __restrict__ c_ws) {
  const int z = blockIdx.z;
  const u16* A = xh_cur + (size_t)z*BATCH*1024;
  const u16* W = Wc + (size_t)z*H4*1024;
  const float* bias = bc + (size_t)z*H4;
  float* Cst = c_ws + (size_t)z*BH;
  u16* Hd = xh_nxt + (size_t)z*BATCH*1024;
  const int m0 = blockIdx.y*64, n0 = blockIdx.x*128;

  __shared__ __align__(16) char smem[32768];
  u16* As = (u16*)smem;                        // [64][72]
  u16* Bs = (u16*)(smem + 9216);               // [128][72]

  const int tid = threadIdx.x;
  const int wave = tid>>6, lane = tid&63;
  const int wm = (wave>>1)*32, wn = (wave&1)*64;
  const int m16 = lane&15, quad = lane>>4;

  f32x4 acc[2][4];
  #pragma unroll
  for (int i=0;i<2;i++)
    #pragma unroll
    for (int j=0;j<4;j++) acc[i][j] = (f32x4){0.f,0.f,0.f,0.f};

  for (int kt = 0; kt < 1024; kt += 64) {
    uint4 av[2], wv[4];
    #pragma unroll
    for (int it=0; it<2; it++){
      int idx = tid + it*256;
      int r = idx>>3, c = idx&7;
      av[it] = *(const uint4*)(A + (size_t)(m0+r)*1024 + kt + c*8);
    }
    #pragma unroll
    for (int it=0; it<4; it++){
      int idx = tid + it*256;
      int r = idx>>3, c = idx&7;
      wv[it] = *(const uint4*)(W + (size_t)(n0+r)*1024 + kt + c*8);
    }
    __syncthreads();
    #pragma unroll
    for (int it=0; it<2; it++){
      int idx = tid + it*256; int r = idx>>3, c = idx&7;
      *(uint4*)&As[r*72 + c*8] = av[it];
    }
    #pragma unroll
    for (int it=0; it<4; it++){
      int idx = tid + it*256; int r = idx>>3, c = idx&7;
      *(uint4*)&Bs[r*72 + c*8] = wv[it];
    }
    __syncthreads();
    #pragma unroll
    for (int ks=0; ks<2; ks++){
      bf16x8 af[2], bfr[4];
      #pragma unroll
      for (int i=0;i<2;i++) af[i] = *(const bf16x8*)&As[(wm + i*16 + m16)*72 + ks*32 + quad*8];
      #pragma unroll
      for (int j=0;j<4;j++) bfr[j] = *(const bf16x8*)&Bs[(wn + j*16 + m16)*72 + ks*32 + quad*8];
      #pragma unroll
      for (int i=0;i<2;i++)
        #pragma unroll
        for (int j=0;j<4;j++)
          acc[i][j] = __builtin_amdgcn_mfma_f32_16x16x32_bf16(af[i], bfr[j], acc[i][j], 0, 0, 0);
    }
  }

  __syncthreads();
  float* epi = (float*)smem;                   // [64][128]
  #pragma unroll
  for (int i=0;i<2;i++){
    int mb = wm + i*16 + quad*4;
    #pragma unroll
    for (int j=0;j<4;j++){
      int cb = wn + j*16 + m16;
      #pragma unroll
      for (int r=0;r<4;r++) epi[(mb+r)*128 + cb] = acc[i][j][r];
    }
  }
  __syncthreads();
  #pragma unroll
  for (int k=0;k<8;k++){
    int p = tid + k*256;
    int u = p & 31, row = p >> 5;
    float4 gv = *(const float4*)&epi[row*128 + u*4];
    int bcol = n0 + u*4;
    float gi = gv.x + bias[bcol+0];
    float gf = gv.y + bias[bcol+1];
    float gg = gv.z + bias[bcol+2];
    float go = gv.w + bias[bcol+3];
    int brow = m0 + row;
    int jj = (n0>>2) + u;
    size_t ci = (size_t)brow*HDIM + jj;
    float cp = Cst[ci];
    float c2 = sigmoidf_(gf)*cp + sigmoidf_(gi)*tanhf(gg);
    float h2 = sigmoidf_(go)*tanhf(c2);
    Cst[ci] = c2;
    Hd[(size_t)brow*1024 + 512 + jj] = f2b(h2);
  }
}

// ---------------------------------------------------------------------------
// prologue helpers
// ---------------------------------------------------------------------------
__global__ void f2b_kernel(const float* __restrict__ src, u16* __restrict__ dst, int n4){
  int i = blockIdx.x*blockDim.x + threadIdx.x;
  if (i >= n4) return;
  float4 v = *(const float4*)(src + (size_t)i*4);
  ushort4 o; o.x=f2b(v.x); o.y=f2b(v.y); o.z=f2b(v.z); o.w=f2b(v.w);
  *(ushort4*)(dst + (size_t)i*4) = o;
}

__global__ void remap_kernel(const float* __restrict__ src, u16* __restrict__ dst){
  int i = blockIdx.x*blockDim.x + threadIdx.x;
  if (i >= (S_LEN*BATCH*HDIM)/4) return;
  int elem = i*4;
  int s = elem >> 18;
  int b = (elem >> 9) & 511;
  int h = elem & 511;
  float4 v = *(const float4*)(src + (size_t)s*BATCH*HDIM + (size_t)b*HDIM + h);
  ushort4 o; o.x=f2b(v.x); o.y=f2b(v.y); o.z=f2b(v.z); o.w=f2b(v.w);
  *(ushort4*)(dst + ((size_t)b*S_LEN + s)*HDIM + h) = o;
}

__global__ void wperm_kernel(const float* __restrict__ Wih, const float* __restrict__ Whh,
                             u16* __restrict__ Wc){
  int i = blockIdx.x*blockDim.x + threadIdx.x;
  if (i >= H4*256) return;
  int elem = i*4;
  int r = elem >> 10;
  int c = elem & 1023;
  int srcrow = (r&3)*512 + (r>>2);
  const float* src = (c < 512) ? (Wih + (size_t)srcrow*512 + c)
                               : (Whh + (size_t)srcrow*512 + (c-512));
  float4 v = *(const float4*)src;
  ushort4 o; o.x=f2b(v.x); o.y=f2b(v.y); o.z=f2b(v.z); o.w=f2b(v.w);
  *(ushort4*)(Wc + elem) = o;
}

__global__ void bcomb_kernel(const float* __restrict__ bih, const float* __restrict__ bhh,
                             const float* __restrict__ biha, const float* __restrict__ bhha,
                             float* __restrict__ bc){
  int i = blockIdx.x*blockDim.x + threadIdx.x;
  if (i >= 2*H4) return;
  int z = i >> 11, r = i & 2047;
  int srcrow = (r&3)*512 + (r>>2);
  bc[i] = (z ? biha : bih)[srcrow] + (z ? bhha : bhh)[srcrow];
}

__global__ void init_kernel(const float* __restrict__ h0, const float* __restrict__ c0,
                            const float* __restrict__ h0a, const float* __restrict__ c0a,
                            const float* __restrict__ dec, const unsigned char* __restrict__ vmask,
                            u16* __restrict__ xh0, float* __restrict__ c_ws,
                            int* __restrict__ mask){
  for (int i = blockIdx.x*blockDim.x + threadIdx.x; i < BH; i += gridDim.x*blockDim.x) {
    int b = i >> 9, j = i & 511;
    u16 d = f2b(dec[i]);
    xh0[(size_t)b*1024 + j] = d;
    xh0[(size_t)(BATCH+b)*1024 + j] = d;
    xh0[(size_t)b*1024 + 512 + j] = f2b(h0[i]);
    xh0[(size_t)(BATCH+b)*1024 + 512 + j] = f2b(h0a[i]);
    c_ws[i] = c0[i]; c_ws[BH+i] = c0a[i];
    if (i < BS) mask[i] = vmask[i] ? 1 : 0;
  }
}

__global__ __launch_bounds__(64) void mask_fix_kernel(int* __restrict__ mask){
  int b = blockIdx.x, lane = threadIdx.x;
  int mv = (lane < S_LEN) ? mask[b*S_LEN+lane] : 1;
  unsigned long long bal = __ballot(mv != 0);
  if ((bal & MASK50) == MASK50 && lane == 49) mask[b*S_LEN+49] = 0;
}

// ---------------------------------------------------------------------------
// Fallback fused attention tail (R4, 512 threads / 8 waves).
// ---------------------------------------------------------------------------
__global__ __launch_bounds__(512) void attn_fused_kernel(
    const float* __restrict__ qpart,
    const float* __restrict__ bq_g, const float* __restrict__ bq_ga,
    const u16* __restrict__ e_g, const u16* __restrict__ e_ga,
    const float* __restrict__ v_g, const float* __restrict__ v_ga,
    const u16* __restrict__ F_m, const u16* __restrict__ F_a,
    const float* __restrict__ bq_p, const float* __restrict__ bq_pa,
    const u16* __restrict__ e_p, const u16* __restrict__ e_pa,
    const float* __restrict__ v_p, const float* __restrict__ v_pa,
    int* __restrict__ mask,
    const u16* __restrict__ emb_bf, const u16* __restrict__ ench_bf,
    u16* __restrict__ xh_nxt, float* __restrict__ out, int t){
  int b = blockIdx.x, tid = threadIdx.x;
  int w = tid>>6, lane = tid&63;
  int z = w>>2, wz = w&3;
  __shared__ float sh_lg[2][64];
  __shared__ float sh_q2[2][HDIM];
  __shared__ float sh_lp[2][64];
  __shared__ int idx_sh;

  const u16* eg = (z ? e_ga : e_g) + (size_t)b*S_LEN*HDIM;
  const float* vg  = z ? v_ga : v_g;
  const float* bqg = z ? bq_ga : bq_g;
  const float* qp = qpart + (size_t)z*KSPQ*BH + (size_t)b*HDIM;
  int h0 = lane*8;
  float qreg[8], vreg[8];
  #pragma unroll
  for (int ii=0; ii<8; ii++){
    int h = h0+ii;
    float q = bqg[h];
    #pragma unroll
    for (int p=0;p<KSPQ;p++) q += qp[(size_t)p*BH + h];
    qreg[ii]=q; vreg[ii]=vg[h];
  }
  for (int s = wz; s < S_LEN; s += 4) {
    uint4 ev = *(const uint4*)(eg + (size_t)s*HDIM + h0);
    const u16* pe = (const u16*)&ev;
    float acc = 0.0f;
    #pragma unroll
    for (int ii=0; ii<8; ii++) acc += vreg[ii]*tanhf(qreg[ii] + b2f(pe[ii]));
    acc = wave_sum(acc);
    if (lane==0) sh_lg[z][s] = mask[b*S_LEN+s] ? -INFINITY : acc;
  }
  __syncthreads();
  if (w < 2) {
    float val = (lane < S_LEN) ? sh_lg[w][lane] : -INFINITY;
    float mx = wave_max(val);
    float ex = (lane < S_LEN) ? expf(val - mx) : 0.0f;
    float sm = wave_sum(ex);
    if (lane < S_LEN) sh_lg[w][lane] = ex / sm;
  }
  __syncthreads();
  #pragma unroll
  for (int zz=0; zz<2; zz++){
    const u16* F = (zz ? F_a : F_m) + (size_t)b*S_LEN*HDIM;
    float acc = (zz ? bq_pa : bq_p)[tid];
    for (int s=0;s<S_LEN;s++) acc += sh_lg[zz][s]*b2f(F[(size_t)s*HDIM + tid]);
    sh_q2[zz][tid] = acc;
  }
  __syncthreads();
  const u16* ep = (z ? e_pa : e_p) + (size_t)b*S_LEN*HDIM;
  const float* vp = z ? v_pa : v_p;
  float q2reg[8], vpreg[8];
  #pragma unroll
  for (int ii=0; ii<8; ii++){ q2reg[ii]=sh_q2[z][h0+ii]; vpreg[ii]=vp[h0+ii]; }
  for (int s = wz; s < S_LEN; s += 4) {
    uint4 ev = *(const uint4*)(ep + (size_t)s*HDIM + h0);
    const u16* pe = (const u16*)&ev;
    float acc = 0.0f;
    #pragma unroll
    for (int ii=0; ii<8; ii++) acc += vpreg[ii]*tanhf(q2reg[ii] + b2f(pe[ii]));
    acc = wave_sum(acc);
    if (lane==0) sh_lp[z][s] = mask[b*S_LEN+s] ? -INFINITY : 10.0f*tanhf(acc);
  }
  __syncthreads();
  if (tid < 64) {
    float a  = (lane < S_LEN) ? sh_lp[0][lane] : -INFINITY;
    float ca = (lane < S_LEN) ? sh_lp[1][lane] : -INFINITY;
    float m1 = wave_max(a);
    float l1 = logf(wave_sum((lane < S_LEN) ? expf(a - m1) : 0.0f));
    float m2 = wave_max(ca);
    float l2 = logf(wave_sum((lane < S_LEN) ? expf(ca - m2) : 0.0f));
    float logp = (a - m1 - l1) + 0.1f * (ca - m2 - l2);
    if (lane < S_LEN) out[(size_t)b*(S_LEN*S_LEN) + t*S_LEN + lane] = fmaxf(logp, -1e30f);
    float vv = (lane < S_LEN) ? logp : -INFINITY;
    int bi = lane;
    #pragma unroll
    for (int o=32;o;o>>=1) {
      float ov = __shfl_xor(vv, o); int oi = __shfl_xor(bi, o);
      if (ov > vv || (ov == vv && oi < bi)) { vv = ov; bi = oi; }
    }
    int idx = bi;
    if (lane == 0) { out[(size_t)BATCH*S_LEN*S_LEN + b*S_LEN + t] = (float)idx; idx_sh = idx; }
    int mv = 1;
    if (lane < S_LEN) { mv = mask[b*S_LEN+lane]; if (lane==idx) mv = 1; mask[b*S_LEN+lane] = mv; }
    unsigned long long bal = __ballot(mv != 0);
    if ((bal & MASK50) == MASK50 && lane == 49) mask[b*S_LEN+49] = 0;
  }
  __syncthreads();
  int idx = idx_sh;
  const u16* esrc = emb_bf  + ((size_t)idx*BATCH + b)*HDIM;
  const u16* asrc = ench_bf + ((size_t)idx*BATCH + b)*HDIM;
  for (int e0 = tid; e0 < HDIM; e0 += 512) {
    xh_nxt[(size_t)b*1024 + e0] = esrc[e0];
    xh_nxt[(size_t)(BATCH+b)*1024 + e0] = asrc[e0];
  }
}

// ---------------------------------------------------------------------------
// Persistent cooperative decode kernel. 512 blocks x 256 threads (2/CU).
// ---------------------------------------------------------------------------
struct PArgs {
  const u16 *Wc; const float *bc;
  u16 *xh0, *xh1;
  const float *c_ws;
  const u16 *Wqg, *Wqga;
  float *q_ws;
  const float *bq_g, *bq_ga, *v_g, *v_ga;
  const u16 *e_g, *e_ga;
  const u16 *F_m, *F_a;
  const float *bq_p, *bq_pa, *v_p, *v_pa;
  const u16 *e_p, *e_pa;
  const int *mask;
  const u16 *emb, *ench;
  float *out;
};

// 64x64 output tile GEMM inner: 4 waves in 2x2 of 32x32, acc 2x2 frags.
__device__ __forceinline__ void gemm64(const u16* __restrict__ A, int lda,
                                       const u16* __restrict__ W, int ldw,
                                       int kbeg, int kend,
                                       u16* As, u16* Bs, f32x4 (&acc)[2][2], int tid){
  const int wv = tid>>6, lane = tid&63;
  const int wm = (wv>>1)*32, wn = (wv&1)*32;
  const int m16 = lane&15, quad = lane>>4;
  for (int kt=kbeg; kt<kend; kt+=64){
    uint4 av[2], bv[2];
    #pragma unroll
    for (int it=0; it<2; it++){
      int idx = tid + it*256, r = idx>>3, c = idx&7;
      av[it] = *(const uint4*)(A + (size_t)r*lda + kt + c*8);
      bv[it] = *(const uint4*)(W + (size_t)r*ldw + kt + c*8);
    }
    __syncthreads();
    #pragma unroll
    for (int it=0; it<2; it++){
      int idx = tid + it*256, r = idx>>3, c = idx&7;
      *(uint4*)&As[r*72 + c*8] = av[it];
      *(uint4*)&Bs[r*72 + c*8] = bv[it];
    }
    __syncthreads();
    #pragma unroll
    for (int ks=0; ks<2; ks++){
      bf16x8 af[2], bfr[2];
      #pragma unroll
      for (int i=0;i<2;i++) af[i] = *(const bf16x8*)&As[(wm+i*16+m16)*72 + ks*32 + quad*8];
      #pragma unroll
      for (int j=0;j<2;j++) bfr[j] = *(const bf16x8*)&Bs[(wn+j*16+m16)*72 + ks*32 + quad*8];
      #pragma unroll
      for (int i=0;i<2;i++)
        #pragma unroll
        for (int j=0;j<2;j++)
          acc[i][j] = __builtin_amdgcn_mfma_f32_16x16x32_bf16(af[i], bfr[j], acc[i][j], 0,0,0);
    }
  }
}

__global__ __launch_bounds__(256, 2) void decode_persistent(PArgs P){
  cg::grid_group grid = cg::this_grid();
  const int bid = blockIdx.x, tid = threadIdx.x;
  const int wv = tid>>6, lane = tid&63;
  const int wm = (wv>>1)*32, wn = (wv&1)*32;
  const int m16 = lane&15, quad = lane>>4;

  __shared__ __align__(16) char stg[18432];   // gemm staging / fp32 epi union
  __shared__ float sh_lg[2][64];
  __shared__ float sh_q2[2][HDIM];
  __shared__ float sh_lp[2][64];
  __shared__ int smask[64];
  __shared__ int idx_sh;
  u16* As = (u16*)stg;
  u16* Bs = (u16*)(stg + 9216);
  float* epi = (float*)stg;                   // 64x64 fp32 = 16 KB

  // static mappings
  const int lz = bid>>8, lr = bid&255, lm0 = (lr>>5)*64, ln0 = (lr&31)*64;
  const int qz = bid>>8, qr = bid&255, qksp = qr>>6;
  const int qm0 = ((qr&63)>>3)*64, qn0 = (qr&7)*64;
  const int b = bid;

  // persistent c-state (4 cells per thread; same mapping every step)
  float creg[4];
  #pragma unroll
  for (int k=0;k<4;k++){
    int p = tid + k*256, u = p&15, row = p>>4;
    creg[k] = P.c_ws[(size_t)lz*BH + (size_t)(lm0+row)*HDIM + (ln0>>2) + u];
  }
  if (tid < 64) smask[tid] = (tid < S_LEN) ? P.mask[b*S_LEN + tid] : 1;
  __syncthreads();

  for (int t=0; t<S_LEN; ++t){
    const u16* cur = (t&1) ? P.xh1 : P.xh0;
    u16* nxt = (t&1) ? P.xh0 : P.xh1;

    // ================= phase 1: LSTM (64x64 tile, K=1024) =================
    {
      f32x4 acc[2][2];
      #pragma unroll
      for (int i=0;i<2;i++)
        #pragma unroll
        for (int j=0;j<2;j++) acc[i][j] = (f32x4){0.f,0.f,0.f,0.f};
      gemm64(cur + (size_t)lz*BATCH*1024 + (size_t)lm0*1024, 1024,
             P.Wc + (size_t)lz*H4*1024 + (size_t)ln0*1024, 1024,
             0, 1024, As, Bs, acc, tid);
      __syncthreads();
      #pragma unroll
      for (int i=0;i<2;i++)
        #pragma unroll
        for (int j=0;j<2;j++)
          #pragma unroll
          for (int r=0;r<4;r++)
            epi[(wm+i*16+quad*4+r)*64 + wn+j*16+m16] = acc[i][j][r];
      __syncthreads();
      const float* bias = P.bc + (size_t)lz*H4;
      u16* Hd = nxt + (size_t)lz*BATCH*1024;
      #pragma unroll
      for (int k=0;k<4;k++){
        int p = tid + k*256, u = p&15, row = p>>4;
        float4 gv = *(const float4*)&epi[row*64 + u*4];
        int bcol = ln0 + u*4;
        float gi = gv.x + bias[bcol+0];
        float gf = gv.y + bias[bcol+1];
        float gg = gv.z + bias[bcol+2];
        float go = gv.w + bias[bcol+3];
        float c2 = sigmoidf_(gf)*creg[k] + sigmoidf_(gi)*tanhf(gg);
        creg[k] = c2;
        Hd[(size_t)(lm0+row)*1024 + 512 + (ln0>>2) + u] = f2b(sigmoidf_(go)*tanhf(c2));
      }
    }
    __threadfence();
    grid.sync();

    // ================= phase 2: qg GEMM (split-K=4) =================
    {
      f32x4 acc[2][2];
      #pragma unroll
      for (int i=0;i<2;i++)
        #pragma unroll
        for (int j=0;j<2;j++) acc[i][j] = (f32x4){0.f,0.f,0.f,0.f};
      const u16* Aq = nxt + (size_t)qz*BATCH*1024 + 512 + (size_t)qm0*1024;
      const u16* Wq = (qz ? P.Wqga : P.Wqg) + (size_t)qn0*HDIM;
      gemm64(Aq, 1024, Wq, HDIM, qksp*128, qksp*128+128, As, Bs, acc, tid);
      __syncthreads();
      #pragma unroll
      for (int i=0;i<2;i++)
        #pragma unroll
        for (int j=0;j<2;j++)
          #pragma unroll
          for (int r=0;r<4;r++)
            epi[(wm+i*16+quad*4+r)*64 + wn+j*16+m16] = acc[i][j][r];
      __syncthreads();
      float* Cq = P.q_ws + (size_t)((qz*KSPQ + qksp)*BATCH + qm0)*HDIM + qn0;
      #pragma unroll
      for (int k=0;k<4;k++){
        int p = tid + k*256, c4 = p&15, row = p>>4;
        *(float4*)(Cq + (size_t)row*HDIM + c4*4) = *(const float4*)&epi[row*64 + c4*4];
      }
    }
    __threadfence();
    grid.sync();

    // ================= phase 3: attention + combine + gather =================
    {
      const int z = wv>>1, wz = wv&1;
      const u16* eg = (z ? P.e_ga : P.e_g) + (size_t)b*S_LEN*HDIM;
      const float* vg  = z ? P.v_ga : P.v_g;
      const float* bqg = z ? P.bq_ga : P.bq_g;
      const float* qp  = P.q_ws + (size_t)z*KSPQ*BH + (size_t)b*HDIM;
      int h0 = lane*8;
      float qreg[8], vreg[8];
      #pragma unroll
      for (int ii=0; ii<8; ii++){
        int h = h0+ii;
        float q = bqg[h];
        #pragma unroll
        for (int p=0;p<KSPQ;p++) q += qp[(size_t)p*BH + h];
        qreg[ii]=q; vreg[ii]=vg[h];
      }
      for (int s = wz; s < S_LEN; s += 2){
        uint4 ev = *(const uint4*)(eg + (size_t)s*HDIM + h0);
        const u16* pe = (const u16*)&ev;
        float acc = 0.0f;
        #pragma unroll
        for (int ii=0; ii<8; ii++) acc += vreg[ii]*tanhf(qreg[ii] + b2f(pe[ii]));
        acc = wave_sum(acc);
        if (lane==0) sh_lg[z][s] = smask[s] ? -INFINITY : acc;
      }
      __syncthreads();
      if (wv < 2){
        float val = (lane < S_LEN) ? sh_lg[wv][lane] : -INFINITY;
        float mx = wave_max(val);
        float ex = (lane < S_LEN) ? expf(val - mx) : 0.0f;
        float sm = wave_sum(ex);
        if (lane < S_LEN) sh_lg[wv][lane] = ex / sm;
      }
      __syncthreads();
      #pragma unroll
      for (int zz=0; zz<2; zz++){
        const u16* F = (zz ? P.F_a : P.F_m) + (size_t)b*S_LEN*HDIM;
        for (int hh = tid; hh < HDIM; hh += 256){
          float a2 = (zz ? P.bq_pa : P.bq_p)[hh];
          for (int s=0;s<S_LEN;s++) a2 += sh_lg[zz][s]*b2f(F[(size_t)s*HDIM + hh]);
          sh_q2[zz][hh] = a2;
        }
      }
      __syncthreads();
      const u16* ep = (z ? P.e_pa : P.e_p) + (size_t)b*S_LEN*HDIM;
      const float* vp = z ? P.v_pa : P.v_p;
      float q2r[8], vpr[8];
      #pragma unroll
      for (int ii=0; ii<8; ii++){ q2r[ii]=sh_q2[z][h0+ii]; vpr[ii]=vp[h0+ii]; }
      for (int s = wz; s < S_LEN; s += 2){
        uint4 ev = *(const uint4*)(ep + (size_t)s*HDIM + h0);
        const u16* pe = (const u16*)&ev;
        float acc = 0.0f;
        #pragma unroll
        for (int ii=0; ii<8; ii++) acc += vpr[ii]*tanhf(q2r[ii] + b2f(pe[ii]));
        acc = wave_sum(acc);
        if (lane==0) sh_lp[z][s] = smask[s] ? -INFINITY : 10.0f*tanhf(acc);
      }
      __syncthreads();
      if (tid < 64){
        float a  = (lane < S_LEN) ? sh_lp[0][lane] : -INFINITY;
        float ca = (lane < S_LEN) ? sh_lp[1][lane] : -INFINITY;
        float m1 = wave_max(a);
        float l1 = logf(wave_sum((lane < S_LEN) ? expf(a - m1) : 0.0f));
        float m2 = wave_max(ca);
        float l2 = logf(wave_sum((lane < S_LEN) ? expf(ca - m2) : 0.0f));
        float logp = (a - m1 - l1) + 0.1f * (ca - m2 - l2);
        if (lane < S_LEN) P.out[(size_t)b*(S_LEN*S_LEN) + t*S_LEN + lane] = fmaxf(logp, -1e30f);
        float vvv = (lane < S_LEN) ? logp : -INFINITY;
        int bi = lane;
        #pragma unroll
        for (int o=32;o;o>>=1){
          float ov = __shfl_xor(vvv, o); int oi = __shfl_xor(bi, o);
          if (ov > vvv || (ov == vvv && oi < bi)) { vvv = ov; bi = oi; }
        }
        int idx = bi;
        if (lane == 0){ P.out[(size_t)BATCH*S_LEN*S_LEN + b*S_LEN + t] = (float)idx; idx_sh = idx; }
        int mv = 1;
        if (lane < S_LEN){ mv = smask[lane]; if (lane==idx) mv = 1; smask[lane] = mv; }
        unsigned long long bal = __ballot(mv != 0);
        if ((bal & MASK50) == MASK50 && lane == 49) smask[49] = 0;
      }
      __syncthreads();
      int idx = idx_sh;
      const u16* es = P.emb  + ((size_t)idx*BATCH + b)*HDIM;
      const u16* as2= P.ench + ((size_t)idx*BATCH + b)*HDIM;
      for (int e0 = tid; e0 < HDIM; e0 += 256){
        nxt[(size_t)b*1024 + e0] = es[e0];
        nxt[(size_t)(BATCH+b)*1024 + e0] = as2[e0];
      }
    }
    __threadfence();
    grid.sync();
  }
}

// ---------------------------------------------------------------------------
extern "C" void kernel_launch(void* const* d_in, const int* in_sizes, int n_in,
                              void* d_out, int out_size, void* d_ws, size_t ws_size,
                              hipStream_t stream) {
  (void)in_sizes; (void)n_in; (void)out_size; (void)ws_size;
  const float* dec    = (const float*)d_in[0];
  const float* emb    = (const float*)d_in[1];
  const float* h0     = (const float*)d_in[2];
  const float* c0     = (const float*)d_in[3];
  const float* ctx    = (const float*)d_in[4];
  const float* ench   = (const float*)d_in[5];
  const float* dia    = (const float*)d_in[6];
  const float* h0a    = (const float*)d_in[7];
  const float* c0a    = (const float*)d_in[8];
  const unsigned char* vmask = (const unsigned char*)d_in[9];
  const float* W_ih   = (const float*)d_in[10];
  const float* W_hh   = (const float*)d_in[11];
  const float* b_ih   = (const float*)d_in[12];
  const float* b_hh   = (const float*)d_in[13];
  const float* W_ih_a = (const float*)d_in[14];
  const float* W_hh_a = (const float*)d_in[15];
  const float* b_ih_a = (const float*)d_in[16];
  const float* b_hh_a = (const float*)d_in[17];
  const float* Wq_p  = (const float*)d_in[18];
  const float* bq_p  = (const float*)d_in[19];
  const float* Wr_p  = (const float*)d_in[20];
  const float* br_p  = (const float*)d_in[21];
  const float* v_p   = (const float*)d_in[22];
  const float* Wq_pa = (const float*)d_in[23];
  const float* bq_pa = (const float*)d_in[24];
  const float* Wr_pa = (const float*)d_in[25];
  const float* br_pa = (const float*)d_in[26];
  const float* v_pa  = (const float*)d_in[27];
  const float* Wq_g  = (const float*)d_in[28];
  const float* bq_g  = (const float*)d_in[29];
  const float* Wr_g  = (const float*)d_in[30];
  const float* br_g  = (const float*)d_in[31];
  const float* v_g   = (const float*)d_in[32];
  const float* Wq_ga = (const float*)d_in[33];
  const float* bq_ga = (const float*)d_in[34];
  const float* Wr_ga = (const float*)d_in[35];
  const float* br_ga = (const float*)d_in[36];
  const float* v_ga  = (const float*)d_in[37];

  char* base = (char*)d_ws;
  size_t off = 0;
  auto carve = [&](size_t bytes)->char*{ char* p = base + off; off += (bytes + 255) & ~(size_t)255; return p; };

  const size_t E_BYTES = (size_t)BS*HDIM*2;
  u16* e_g   = (u16*)carve(E_BYTES);
  u16* e_p   = (u16*)carve(E_BYTES);
  u16* e_ga  = (u16*)carve(E_BYTES);
  u16* e_pa  = (u16*)carve(E_BYTES);
  u16* F_m   = (u16*)carve(E_BYTES);
  u16* F_a   = (u16*)carve(E_BYTES);
  char* scratch = carve(2*E_BYTES);
  u16* A_ctx  = (u16*)scratch;
  u16* A_dia  = (u16*)(scratch + E_BYTES);
  u16* emb_bf  = A_ctx;
  u16* ench_bf = A_dia;
  u16* Wc      = (u16*)carve((size_t)2*H4*1024*2);
  float* bc    = (float*)carve((size_t)2*H4*4);
  u16* Wqg_bf  = (u16*)carve((size_t)BH*2);
  u16* Wqga_bf = (u16*)carve((size_t)BH*2);
  u16* Wqp_bf  = (u16*)carve((size_t)BH*2);
  u16* Wqpa_bf = (u16*)carve((size_t)BH*2);
  u16* Wrg_bf  = (u16*)carve((size_t)BH*2);
  u16* Wrp_bf  = (u16*)carve((size_t)BH*2);
  u16* Wrga_bf = (u16*)carve((size_t)BH*2);
  u16* Wrpa_bf = (u16*)carve((size_t)BH*2);
  u16* xh0     = (u16*)carve((size_t)2*BATCH*1024*2);
  u16* xh1     = (u16*)carve((size_t)2*BATCH*1024*2);
  float* c_ws  = (float*)carve((size_t)2*BH*4);
  float* q_ws  = (float*)carve((size_t)2*KSPQ*BH*4);
  int*   mask  = (int*)carve((size_t)BS*4);
  float* out   = (float*)d_out;

  init_kernel<<<1024, 256, 0, stream>>>(h0, c0, h0a, c0a, dec, vmask, xh0, c_ws, mask);
  mask_fix_kernel<<<BATCH, 64, 0, stream>>>(mask);

  const int RB = ((S_LEN*BATCH*HDIM/4)+255)/256;
  remap_kernel<<<RB, 256, 0, stream>>>(ctx, A_ctx);
  remap_kernel<<<RB, 256, 0, stream>>>(dia, A_dia);
  const int NWQ = BH/4;
  f2b_kernel<<<(NWQ+255)/256, 256, 0, stream>>>(Wq_g,  Wqg_bf,  NWQ);
  f2b_kernel<<<(NWQ+255)/256, 256, 0, stream>>>(Wq_ga, Wqga_bf, NWQ);
  f2b_kernel<<<(NWQ+255)/256, 256, 0, stream>>>(Wq_p,  Wqp_bf,  NWQ);
  f2b_kernel<<<(NWQ+255)/256, 256, 0, stream>>>(Wq_pa, Wqpa_bf, NWQ);
  f2b_kernel<<<(NWQ+255)/256, 256, 0, stream>>>(Wr_g,  Wrg_bf,  NWQ);
  f2b_kernel<<<(NWQ+255)/256, 256, 0, stream>>>(Wr_p,  Wrp_bf,  NWQ);
  f2b_kernel<<<(NWQ+255)/256, 256, 0, stream>>>(Wr_ga, Wrga_bf, NWQ);
  f2b_kernel<<<(NWQ+255)/256, 256, 0, stream>>>(Wr_pa, Wrpa_bf, NWQ);
  wperm_kernel<<<(H4*256+255)/256, 256, 0, stream>>>(W_ih,   W_hh,   Wc);
  wperm_kernel<<<(H4*256+255)/256, 256, 0, stream>>>(W_ih_a, W_hh_a, Wc + (size_t)H4*1024);
  bcomb_kernel<<<(2*H4+255)/256, 256, 0, stream>>>(b_ih, b_hh, b_ih_a, b_hh_a, bc);

  MArgs pa{};
  pa.A[0]=A_ctx; pa.A[1]=A_ctx; pa.A[2]=A_dia; pa.A[3]=A_dia;
  pa.W[0]=Wrg_bf; pa.W[1]=Wrp_bf; pa.W[2]=Wrga_bf; pa.W[3]=Wrpa_bf;
  pa.bias[0]=br_g; pa.bias[1]=br_p; pa.bias[2]=br_ga; pa.bias[3]=br_pa;
  pa.C[0]=e_g; pa.C[1]=e_p; pa.C[2]=e_ga; pa.C[3]=e_pa;
  pa.M=BS; pa.N=HDIM; pa.K=HDIM; pa.lda=HDIM; pa.ksplit=1; pa.out_bf16=1;
  mfma_gemm<<<dim3(4,200,4), 256, 0, stream>>>(pa);

  const int NE = S_LEN*BATCH*HDIM/4;
  f2b_kernel<<<(NE+255)/256, 256, 0, stream>>>(emb,  emb_bf,  NE);
  f2b_kernel<<<(NE+255)/256, 256, 0, stream>>>(ench, ench_bf, NE);

  MArgs fa{};
  fa.A[0]=e_g; fa.A[1]=e_ga;
  fa.W[0]=Wqp_bf; fa.W[1]=Wqpa_bf;
  fa.bias[0]=fa.bias[1]=nullptr;
  fa.C[0]=F_m; fa.C[1]=F_a;
  fa.M=BS; fa.N=HDIM; fa.K=HDIM; fa.lda=HDIM; fa.ksplit=1; fa.out_bf16=1;
  mfma_gemm<<<dim3(4,200,2), 256, 0, stream>>>(fa);

  // ---- persistent cooperative decode loop ----
  PArgs pp{};
  pp.Wc = Wc; pp.bc = bc;
  pp.xh0 = xh0; pp.xh1 = xh1;
  pp.c_ws = c_ws;
  pp.Wqg = Wqg_bf; pp.Wqga = Wqga_bf;
  pp.q_ws = q_ws;
  pp.bq_g = bq_g; pp.bq_ga = bq_ga; pp.v_g = v_g; pp.v_ga = v_ga;
  pp.e_g = e_g; pp.e_ga = e_ga;
  pp.F_m = F_m; pp.F_a = F_a;
  pp.bq_p = bq_p; pp.bq_pa = bq_pa; pp.v_p = v_p; pp.v_pa = v_pa;
  pp.e_p = e_p; pp.e_pa = e_pa;
  pp.mask = mask;
  pp.emb = emb_bf; pp.ench = ench_bf;
  pp.out = out;
  void* kargs[] = { (void*)&pp };
  hipError_t cerr = hipLaunchCooperativeKernel((const void*)decode_persistent,
                                               dim3(512), dim3(256), kargs, 0, stream);
  if (cerr == hipSuccess) return;
  (void)hipGetLastError();   // clear, take fallback dispatch loop

  // ---- fallback: R4 three-dispatch step loop ----
  MArgs qgE{};
  qgE.A[0]=xh1+512; qgE.A[1]=xh1+(size_t)BATCH*1024+512;
  qgE.W[0]=Wqg_bf; qgE.W[1]=Wqga_bf;
  qgE.bias[0]=qgE.bias[1]=nullptr;
  qgE.C[0]=q_ws; qgE.C[1]=q_ws+(size_t)KSPQ*BH;
  qgE.M=BATCH; qgE.N=HDIM; qgE.K=HDIM; qgE.lda=1024; qgE.ksplit=KSPQ; qgE.out_bf16=0;
  MArgs qgO = qgE;
  qgO.A[0]=xh0+512; qgO.A[1]=xh0+(size_t)BATCH*1024+512;

  for (int t = 0; t < S_LEN; ++t) {
    u16* cur = (t&1) ? xh1 : xh0;
    u16* nxt = (t&1) ? xh0 : xh1;
    lstm_gemm<<<dim3(16,8,2), 256, 0, stream>>>(cur, nxt, Wc, bc, c_ws);
    mfma_gemm<<<dim3(4,4*KSPQ,2), 256, 0, stream>>>((t&1) ? qgO : qgE);
    attn_fused_kernel<<<BATCH, 512, 0, stream>>>(
        q_ws, bq_g, bq_ga, e_g, e_ga, v_g, v_ga,
        F_m, F_a, bq_p, bq_pa, e_p, e_pa, v_p, v_pa,
        mask, emb_bf, ench_bf, nxt, out, t);
  }
}

// Round 3
// 7282.581 us; speedup vs baseline: 3.0233x; 3.0233x over previous
//
#include <hip/hip_runtime.h>
#include <math.h>

// ---------------------------------------------------------------------------
// Pointer-network decoder, 50 sequential greedy-decode steps.
// R6: back to the dispatch loop (persistent/coop kernel measured 3.4x WORSE:
// grid.sync => L2 invalidate across 8 XCDs => 102 MB HBM refetch per step).
// Structure: 5 dispatches/step =
//   lstm_gemm (concat-K [x|h], gate-interleaved W, fused LSTM nonlinearity)
//   qg GEMM (split-K fp32 partials)
//   glimpse kernel (logits+softmax+weighted sum -> gl bf16)
//   qp GEMM (gl @ Wq_p^T, split-K)   <- F-trick dropped: it cost 52 MB/step
//   pointer+combine+gather fused
// pa projection GEMM keeps the R5 epilogue fix (LDS-staged coalesced bf16
// stores; was 8x write-amplified). fa prologue GEMM is gone.
// ---------------------------------------------------------------------------

#define S_LEN 50
#define BATCH 512
#define HDIM  512
#define H4    2048
#define BH    (BATCH*HDIM)          // 262144
#define BS    (BATCH*S_LEN)         // 25600
#define KSPQ  4
#define MASK50 0x0003FFFFFFFFFFFFULL

typedef unsigned short u16;
typedef __attribute__((ext_vector_type(8))) short bf16x8;
typedef __attribute__((ext_vector_type(4))) float f32x4;

__device__ __forceinline__ float wave_sum(float v){
  #pragma unroll
  for (int o=32;o;o>>=1) v += __shfl_xor(v,o);
  return v;
}
__device__ __forceinline__ float wave_max(float v){
  #pragma unroll
  for (int o=32;o;o>>=1) v = fmaxf(v,__shfl_xor(v,o));
  return v;
}
__device__ __forceinline__ float sigmoidf_(float x){ return 1.0f/(1.0f+expf(-x)); }
__device__ __forceinline__ u16 f2b(float f){
  unsigned u = __float_as_uint(f);
  unsigned r = (u + 0x7fffu + ((u>>16)&1u)) >> 16;
  return (u16)r;
}
__device__ __forceinline__ float b2f(u16 h){ return __uint_as_float(((unsigned)h)<<16); }

// ---------------------------------------------------------------------------
// Generic bf16 MFMA GEMM: C[m,n] = sum_k A[m,k]*W[n,k] (+bias[n]).
// A rows at stride lda (bf16), W row-major [N,K]. 128x128 tile, BK=64,
// 256 thr = 4 waves (2x2 of 64x64), each wave 4x4 MFMA tiles.
// ksplit: blockIdx.y = mtile*ksplit+ksp; fp32 partial at C + ksp*M*N.
// bf16 output path: LDS-staged, coalesced uint4 stores (write-amp fix).
// ---------------------------------------------------------------------------
struct MArgs {
  const u16* A[4]; const u16* W[4]; const float* bias[4]; void* C[4];
  int M, N, K, lda, ksplit, out_bf16;
};

__global__ __launch_bounds__(256, 2) void mfma_gemm(MArgs g) {
  const int z = blockIdx.z;
  const u16* __restrict__ A = g.A[z];
  const u16* __restrict__ W = g.W[z];
  const float* __restrict__ bias = g.bias[z];
  const int N = g.N, K = g.K, lda = g.lda;
  const int mtile = blockIdx.y / g.ksplit;
  const int ksp   = blockIdx.y % g.ksplit;
  const int m0 = mtile*128, n0 = blockIdx.x*128;
  const int kc = K / g.ksplit;
  const int kbeg = ksp*kc, kend = kbeg+kc;

  __shared__ __align__(16) u16 sh[2*128*88];
  u16* As = sh;
  u16* Bs = sh + 128*88;

  const int tid = threadIdx.x;
  const int wave = tid>>6, lane = tid&63;
  const int wm = (wave>>1)*64, wn = (wave&1)*64;
  const int m16 = lane&15, quad = lane>>4;

  f32x4 acc[4][4];
  #pragma unroll
  for (int i=0;i<4;i++)
    #pragma unroll
    for (int j=0;j<4;j++) acc[i][j] = (f32x4){0.f,0.f,0.f,0.f};

  for (int kt = kbeg; kt < kend; kt += 64) {
    uint4 av[4], wv[4];
    #pragma unroll
    for (int it=0; it<4; it++){
      int idx = tid + it*256;
      int r = idx>>3, c = idx&7;
      av[it] = *(const uint4*)(A + (size_t)(m0+r)*lda + kt + c*8);
      wv[it] = *(const uint4*)(W + (size_t)(n0+r)*K + kt + c*8);
    }
    __syncthreads();
    #pragma unroll
    for (int it=0; it<4; it++){
      int idx = tid + it*256;
      int r = idx>>3, c = idx&7;
      *(uint4*)&As[r*88 + c*8] = av[it];
      *(uint4*)&Bs[r*88 + c*8] = wv[it];
    }
    __syncthreads();
    #pragma unroll
    for (int ks=0; ks<2; ks++){
      bf16x8 af[4], bfr[4];
      #pragma unroll
      for (int i=0;i<4;i++) af[i] = *(const bf16x8*)&As[(wm + i*16 + m16)*88 + ks*32 + quad*8];
      #pragma unroll
      for (int j=0;j<4;j++) bfr[j] = *(const bf16x8*)&Bs[(wn + j*16 + m16)*88 + ks*32 + quad*8];
      #pragma unroll
      for (int i=0;i<4;i++)
        #pragma unroll
        for (int j=0;j<4;j++)
          acc[i][j] = __builtin_amdgcn_mfma_f32_16x16x32_bf16(af[i], bfr[j], acc[i][j], 0, 0, 0);
    }
  }

  if (g.out_bf16) {
    // stage bf16 tile (bias added) in LDS, then write coalesced uint4 rows
    u16* C = (u16*)g.C[z];
    __syncthreads();
    #pragma unroll
    for (int i=0;i<4;i++){
      #pragma unroll
      for (int j=0;j<4;j++){
        int cc = wn + j*16 + m16;
        float bv = bias ? bias[n0 + cc] : 0.0f;
        #pragma unroll
        for (int r=0;r<4;r++)
          sh[(wm + i*16 + quad*4 + r)*128 + cc] = f2b(acc[i][j][r] + bv);
      }
    }
    __syncthreads();
    #pragma unroll
    for (int k=0;k<8;k++){
      int idx = tid + k*256;
      int row = idx>>4, c = idx&15;
      *(uint4*)(C + (size_t)(m0+row)*N + n0 + c*8) = *(const uint4*)&sh[row*128 + c*8];
    }
  } else {
    float* C = (float*)g.C[z] + (size_t)ksp*g.M*N;
    #pragma unroll
    for (int i=0;i<4;i++){
      int mb = m0 + wm + i*16 + quad*4;
      #pragma unroll
      for (int j=0;j<4;j++){
        int n = n0 + wn + j*16 + m16;
        float bv = bias ? bias[n] : 0.0f;
        #pragma unroll
        for (int r=0;r<4;r++)
          C[(size_t)(mb+r)*N + n] = acc[i][j][r] + bv;
      }
    }
  }
}

// ---------------------------------------------------------------------------
// LSTM GEMM: g = [x|h] @ Wc^T (K=1024) with gate-interleaved Wc rows
// (row 4j+g = unit j, gate g), then LSTM nonlinearity in-block.
// Tile 64(M) x 128(N) -> 32 complete units per tile; 256 blocks (16x8x2).
// Reads xh_cur [2][B][1024] bf16; writes h into xh_nxt[:, 512:1024] (bf16)
// and c (fp32) in place. Ping-pong avoids the read/write race on h.
// ---------------------------------------------------------------------------
__global__ __launch_bounds__(256, 2) void lstm_gemm(
    const u16* __restrict__ xh_cur, u16* __restrict__ xh_nxt,
    const u16* __restrict__ Wc, const float* __restrict__ bc,
    float* __restrict__ c_ws) {
  const int z = blockIdx.z;
  const u16* A = xh_cur + (size_t)z*BATCH*1024;
  const u16* W = Wc + (size_t)z*H4*1024;
  const float* bias = bc + (size_t)z*H4;
  float* Cst = c_ws + (size_t)z*BH;
  u16* Hd = xh_nxt + (size_t)z*BATCH*1024;
  const int m0 = blockIdx.y*64, n0 = blockIdx.x*128;

  __shared__ __align__(16) char smem[32768];
  u16* As = (u16*)smem;                        // [64][72]
  u16* Bs = (u16*)(smem + 9216);               // [128][72]

  const int tid = threadIdx.x;
  const int wave = tid>>6, lane = tid&63;
  const int wm = (wave>>1)*32, wn = (wave&1)*64;
  const int m16 = lane&15, quad = lane>>4;

  f32x4 acc[2][4];
  #pragma unroll
  for (int i=0;i<2;i++)
    #pragma unroll
    for (int j=0;j<4;j++) acc[i][j] = (f32x4){0.f,0.f,0.f,0.f};

  for (int kt = 0; kt < 1024; kt += 64) {
    uint4 av[2], wv[4];
    #pragma unroll
    for (int it=0; it<2; it++){
      int idx = tid + it*256;
      int r = idx>>3, c = idx&7;
      av[it] = *(const uint4*)(A + (size_t)(m0+r)*1024 + kt + c*8);
    }
    #pragma unroll
    for (int it=0; it<4; it++){
      int idx = tid + it*256;
      int r = idx>>3, c = idx&7;
      wv[it] = *(const uint4*)(W + (size_t)(n0+r)*1024 + kt + c*8);
    }
    __syncthreads();
    #pragma unroll
    for (int it=0; it<2; it++){
      int idx = tid + it*256; int r = idx>>3, c = idx&7;
      *(uint4*)&As[r*72 + c*8] = av[it];
    }
    #pragma unroll
    for (int it=0; it<4; it++){
      int idx = tid + it*256; int r = idx>>3, c = idx&7;
      *(uint4*)&Bs[r*72 + c*8] = wv[it];
    }
    __syncthreads();
    #pragma unroll
    for (int ks=0; ks<2; ks++){
      bf16x8 af[2], bfr[4];
      #pragma unroll
      for (int i=0;i<2;i++) af[i] = *(const bf16x8*)&As[(wm + i*16 + m16)*72 + ks*32 + quad*8];
      #pragma unroll
      for (int j=0;j<4;j++) bfr[j] = *(const bf16x8*)&Bs[(wn + j*16 + m16)*72 + ks*32 + quad*8];
      #pragma unroll
      for (int i=0;i<2;i++)
        #pragma unroll
        for (int j=0;j<4;j++)
          acc[i][j] = __builtin_amdgcn_mfma_f32_16x16x32_bf16(af[i], bfr[j], acc[i][j], 0, 0, 0);
    }
  }

  __syncthreads();
  float* epi = (float*)smem;                   // [64][128]
  #pragma unroll
  for (int i=0;i<2;i++){
    int mb = wm + i*16 + quad*4;
    #pragma unroll
    for (int j=0;j<4;j++){
      int cb = wn + j*16 + m16;
      #pragma unroll
      for (int r=0;r<4;r++) epi[(mb+r)*128 + cb] = acc[i][j][r];
    }
  }
  __syncthreads();
  #pragma unroll
  for (int k=0;k<8;k++){
    int p = tid + k*256;
    int u = p & 31, row = p >> 5;
    float4 gv = *(const float4*)&epi[row*128 + u*4];
    int bcol = n0 + u*4;
    float gi = gv.x + bias[bcol+0];
    float gf = gv.y + bias[bcol+1];
    float gg = gv.z + bias[bcol+2];
    float go = gv.w + bias[bcol+3];
    int brow = m0 + row;
    int jj = (n0>>2) + u;
    size_t ci = (size_t)brow*HDIM + jj;
    float cp = Cst[ci];
    float c2 = sigmoidf_(gf)*cp + sigmoidf_(gi)*tanhf(gg);
    float h2 = sigmoidf_(go)*tanhf(c2);
    Cst[ci] = c2;
    Hd[(size_t)brow*1024 + 512 + jj] = f2b(h2);
  }
}

// ---------------------------------------------------------------------------
// prologue helpers
// ---------------------------------------------------------------------------
__global__ void f2b_kernel(const float* __restrict__ src, u16* __restrict__ dst, int n4){
  int i = blockIdx.x*blockDim.x + threadIdx.x;
  if (i >= n4) return;
  float4 v = *(const float4*)(src + (size_t)i*4);
  ushort4 o; o.x=f2b(v.x); o.y=f2b(v.y); o.z=f2b(v.z); o.w=f2b(v.w);
  *(ushort4*)(dst + (size_t)i*4) = o;
}

__global__ void remap_kernel(const float* __restrict__ src, u16* __restrict__ dst){
  int i = blockIdx.x*blockDim.x + threadIdx.x;
  if (i >= (S_LEN*BATCH*HDIM)/4) return;
  int elem = i*4;
  int s = elem >> 18;
  int b = (elem >> 9) & 511;
  int h = elem & 511;
  float4 v = *(const float4*)(src + (size_t)s*BATCH*HDIM + (size_t)b*HDIM + h);
  ushort4 o; o.x=f2b(v.x); o.y=f2b(v.y); o.z=f2b(v.z); o.w=f2b(v.w);
  *(ushort4*)(dst + ((size_t)b*S_LEN + s)*HDIM + h) = o;
}

__global__ void wperm_kernel(const float* __restrict__ Wih, const float* __restrict__ Whh,
                             u16* __restrict__ Wc){
  int i = blockIdx.x*blockDim.x + threadIdx.x;
  if (i >= H4*256) return;
  int elem = i*4;
  int r = elem >> 10;
  int c = elem & 1023;
  int srcrow = (r&3)*512 + (r>>2);
  const float* src = (c < 512) ? (Wih + (size_t)srcrow*512 + c)
                               : (Whh + (size_t)srcrow*512 + (c-512));
  float4 v = *(const float4*)src;
  ushort4 o; o.x=f2b(v.x); o.y=f2b(v.y); o.z=f2b(v.z); o.w=f2b(v.w);
  *(ushort4*)(Wc + elem) = o;
}

__global__ void bcomb_kernel(const float* __restrict__ bih, const float* __restrict__ bhh,
                             const float* __restrict__ biha, const float* __restrict__ bhha,
                             float* __restrict__ bc){
  int i = blockIdx.x*blockDim.x + threadIdx.x;
  if (i >= 2*H4) return;
  int z = i >> 11, r = i & 2047;
  int srcrow = (r&3)*512 + (r>>2);
  bc[i] = (z ? biha : bih)[srcrow] + (z ? bhha : bhh)[srcrow];
}

__global__ void init_kernel(const float* __restrict__ h0, const float* __restrict__ c0,
                            const float* __restrict__ h0a, const float* __restrict__ c0a,
                            const float* __restrict__ dec, const unsigned char* __restrict__ vmask,
                            u16* __restrict__ xh0, float* __restrict__ c_ws,
                            int* __restrict__ mask){
  for (int i = blockIdx.x*blockDim.x + threadIdx.x; i < BH; i += gridDim.x*blockDim.x) {
    int b = i >> 9, j = i & 511;
    u16 d = f2b(dec[i]);
    xh0[(size_t)b*1024 + j] = d;
    xh0[(size_t)(BATCH+b)*1024 + j] = d;
    xh0[(size_t)b*1024 + 512 + j] = f2b(h0[i]);
    xh0[(size_t)(BATCH+b)*1024 + 512 + j] = f2b(h0a[i]);
    c_ws[i] = c0[i]; c_ws[BH+i] = c0a[i];
    if (i < BS) mask[i] = vmask[i] ? 1 : 0;
  }
}

__global__ __launch_bounds__(64) void mask_fix_kernel(int* __restrict__ mask){
  int b = blockIdx.x, lane = threadIdx.x;
  int mv = (lane < S_LEN) ? mask[b*S_LEN+lane] : 1;
  unsigned long long bal = __ballot(mv != 0);
  if ((bal & MASK50) == MASK50 && lane == 49) mask[b*S_LEN+49] = 0;
}

// ---------------------------------------------------------------------------
// Glimpse attention on bf16 e [B,S,H]: logits+mask+softmax+weighted sum.
// q = sum of KSPQ fp32 partials + bq, held in registers (8 contig h per lane).
// ---------------------------------------------------------------------------
__global__ __launch_bounds__(512) void glimpse_kernel(
    const float* __restrict__ qpart,
    const float* __restrict__ bq_g, const float* __restrict__ bq_ga,
    const u16* __restrict__ e_g, const u16* __restrict__ e_ga,
    const float* __restrict__ v_g, const float* __restrict__ v_ga,
    const int* __restrict__ mask, u16* __restrict__ gl_ws){
  int z = blockIdx.y, b = blockIdx.x, tid = threadIdx.x;
  const u16* e = (z ? e_ga : e_g) + (size_t)b*S_LEN*HDIM;
  const float* v  = z ? v_ga : v_g;
  const float* bq = z ? bq_ga : bq_g;
  const float* qp = qpart + (size_t)z*KSPQ*BH + (size_t)b*HDIM;
  __shared__ float lg_sh[64], p_sh[64];
  int w = tid>>6, lane = tid&63;
  int h0 = lane*8;
  float qreg[8], vreg[8];
  #pragma unroll
  for (int ii=0; ii<8; ii++){
    int h = h0+ii;
    float q = bq[h];
    #pragma unroll
    for (int p=0;p<KSPQ;p++) q += qp[(size_t)p*BH + h];
    qreg[ii]=q; vreg[ii]=v[h];
  }
  for (int s = w; s < S_LEN; s += 8) {
    uint4 ev = *(const uint4*)(e + (size_t)s*HDIM + h0);
    const u16* pe = (const u16*)&ev;
    float acc = 0.0f;
    #pragma unroll
    for (int ii=0; ii<8; ii++) acc += vreg[ii]*tanhf(qreg[ii] + b2f(pe[ii]));
    acc = wave_sum(acc);
    if (lane==0) lg_sh[s] = mask[b*S_LEN+s] ? -INFINITY : acc;
  }
  __syncthreads();
  if (tid < 64) {
    float val = (tid < S_LEN) ? lg_sh[tid] : -INFINITY;
    float mx = wave_max(val);
    float ex = (tid < S_LEN) ? expf(val - mx) : 0.0f;
    float sm = wave_sum(ex);
    if (tid < S_LEN) p_sh[tid] = ex / sm;
  }
  __syncthreads();
  float acc = 0.0f;
  for (int s=0;s<S_LEN;s++) acc += p_sh[s]*b2f(e[(size_t)s*HDIM + tid]);
  gl_ws[(size_t)z*BH + (size_t)b*HDIM + tid] = f2b(acc);
}

// ---------------------------------------------------------------------------
// Fused pointer + combine + gather. One block per b, 512 thr = 8 waves;
// waves 0-3 z=0, waves 4-7 z=1. q2 from qp-GEMM split-K partials + bq_p.
// ---------------------------------------------------------------------------
__global__ __launch_bounds__(512) void pointer_combine_kernel(
    const float* __restrict__ q2part,
    const float* __restrict__ bq_p, const float* __restrict__ bq_pa,
    const u16* __restrict__ e_p, const u16* __restrict__ e_pa,
    const float* __restrict__ v_p, const float* __restrict__ v_pa,
    int* __restrict__ mask,
    const u16* __restrict__ emb_bf, const u16* __restrict__ ench_bf,
    u16* __restrict__ xh_nxt, float* __restrict__ out, int t){
  int b = blockIdx.x, tid = threadIdx.x;
  int w = tid>>6, lane = tid&63;
  int z = w>>2, wz = w&3;
  __shared__ float sh_q2[2][HDIM];
  __shared__ float sh_lp[2][64];
  __shared__ int idx_sh;

  // q2[zz][h] = bq + sum of split-K partials (thread tid <-> h)
  #pragma unroll
  for (int zz=0; zz<2; zz++){
    const float* qp = q2part + (size_t)zz*KSPQ*BH + (size_t)b*HDIM;
    float a2 = (zz ? bq_pa : bq_p)[tid];
    #pragma unroll
    for (int p=0;p<KSPQ;p++) a2 += qp[(size_t)p*BH + tid];
    sh_q2[zz][tid] = a2;
  }
  __syncthreads();

  const u16* ep = (z ? e_pa : e_p) + (size_t)b*S_LEN*HDIM;
  const float* vp = z ? v_pa : v_p;
  int h0 = lane*8;
  float q2r[8], vpr[8];
  #pragma unroll
  for (int ii=0; ii<8; ii++){ q2r[ii]=sh_q2[z][h0+ii]; vpr[ii]=vp[h0+ii]; }
  for (int s = wz; s < S_LEN; s += 4) {
    uint4 ev = *(const uint4*)(ep + (size_t)s*HDIM + h0);
    const u16* pe = (const u16*)&ev;
    float acc = 0.0f;
    #pragma unroll
    for (int ii=0; ii<8; ii++) acc += vpr[ii]*tanhf(q2r[ii] + b2f(pe[ii]));
    acc = wave_sum(acc);
    if (lane==0) sh_lp[z][s] = mask[b*S_LEN+s] ? -INFINITY : 10.0f*tanhf(acc);
  }
  __syncthreads();

  if (tid < 64) {
    float a  = (lane < S_LEN) ? sh_lp[0][lane] : -INFINITY;
    float ca = (lane < S_LEN) ? sh_lp[1][lane] : -INFINITY;
    float m1 = wave_max(a);
    float l1 = logf(wave_sum((lane < S_LEN) ? expf(a - m1) : 0.0f));
    float m2 = wave_max(ca);
    float l2 = logf(wave_sum((lane < S_LEN) ? expf(ca - m2) : 0.0f));
    float logp = (a - m1 - l1) + 0.1f * (ca - m2 - l2);
    if (lane < S_LEN) out[(size_t)b*(S_LEN*S_LEN) + t*S_LEN + lane] = fmaxf(logp, -1e30f);
    float vv = (lane < S_LEN) ? logp : -INFINITY;
    int bi = lane;
    #pragma unroll
    for (int o=32;o;o>>=1) {
      float ov = __shfl_xor(vv, o); int oi = __shfl_xor(bi, o);
      if (ov > vv || (ov == vv && oi < bi)) { vv = ov; bi = oi; }
    }
    int idx = bi;
    if (lane == 0) { out[(size_t)BATCH*S_LEN*S_LEN + b*S_LEN + t] = (float)idx; idx_sh = idx; }
    int mv = 1;
    if (lane < S_LEN) { mv = mask[b*S_LEN+lane]; if (lane==idx) mv = 1; mask[b*S_LEN+lane] = mv; }
    unsigned long long bal = __ballot(mv != 0);
    if ((bal & MASK50) == MASK50 && lane == 49) mask[b*S_LEN+49] = 0;
  }
  __syncthreads();

  int idx = idx_sh;
  const u16* esrc = emb_bf  + ((size_t)idx*BATCH + b)*HDIM;
  const u16* asrc = ench_bf + ((size_t)idx*BATCH + b)*HDIM;
  xh_nxt[(size_t)b*1024 + tid]         = esrc[tid];
  xh_nxt[(size_t)(BATCH+b)*1024 + tid] = asrc[tid];
}

// ---------------------------------------------------------------------------
extern "C" void kernel_launch(void* const* d_in, const int* in_sizes, int n_in,
                              void* d_out, int out_size, void* d_ws, size_t ws_size,
                              hipStream_t stream) {
  (void)in_sizes; (void)n_in; (void)out_size; (void)ws_size;
  const float* dec    = (const float*)d_in[0];
  const float* emb    = (const float*)d_in[1];
  const float* h0     = (const float*)d_in[2];
  const float* c0     = (const float*)d_in[3];
  const float* ctx    = (const float*)d_in[4];
  const float* ench   = (const float*)d_in[5];
  const float* dia    = (const float*)d_in[6];
  const float* h0a    = (const float*)d_in[7];
  const float* c0a    = (const float*)d_in[8];
  const unsigned char* vmask = (const unsigned char*)d_in[9];
  const float* W_ih   = (const float*)d_in[10];
  const float* W_hh   = (const float*)d_in[11];
  const float* b_ih   = (const float*)d_in[12];
  const float* b_hh   = (const float*)d_in[13];
  const float* W_ih_a = (const float*)d_in[14];
  const float* W_hh_a = (const float*)d_in[15];
  const float* b_ih_a = (const float*)d_in[16];
  const float* b_hh_a = (const float*)d_in[17];
  const float* Wq_p  = (const float*)d_in[18];
  const float* bq_p  = (const float*)d_in[19];
  const float* Wr_p  = (const float*)d_in[20];
  const float* br_p  = (const float*)d_in[21];
  const float* v_p   = (const float*)d_in[22];
  const float* Wq_pa = (const float*)d_in[23];
  const float* bq_pa = (const float*)d_in[24];
  const float* Wr_pa = (const float*)d_in[25];
  const float* br_pa = (const float*)d_in[26];
  const float* v_pa  = (const float*)d_in[27];
  const float* Wq_g  = (const float*)d_in[28];
  const float* bq_g  = (const float*)d_in[29];
  const float* Wr_g  = (const float*)d_in[30];
  const float* br_g  = (const float*)d_in[31];
  const float* v_g   = (const float*)d_in[32];
  const float* Wq_ga = (const float*)d_in[33];
  const float* bq_ga = (const float*)d_in[34];
  const float* Wr_ga = (const float*)d_in[35];
  const float* br_ga = (const float*)d_in[36];
  const float* v_ga  = (const float*)d_in[37];

  char* base = (char*)d_ws;
  size_t off = 0;
  auto carve = [&](size_t bytes)->char*{ char* p = base + off; off += (bytes + 255) & ~(size_t)255; return p; };

  const size_t E_BYTES = (size_t)BS*HDIM*2;      // 26,214,400
  u16* e_g   = (u16*)carve(E_BYTES);
  u16* e_p   = (u16*)carve(E_BYTES);
  u16* e_ga  = (u16*)carve(E_BYTES);
  u16* e_pa  = (u16*)carve(E_BYTES);
  char* scratch = carve(2*E_BYTES);              // A_ctx/A_dia, later emb/ench bf16
  u16* A_ctx  = (u16*)scratch;
  u16* A_dia  = (u16*)(scratch + E_BYTES);
  u16* emb_bf  = A_ctx;                          // aliases (prologue-ordered)
  u16* ench_bf = A_dia;
  u16* Wc      = (u16*)carve((size_t)2*H4*1024*2);   // gate-interleaved [2][2048][1024]
  float* bc    = (float*)carve((size_t)2*H4*4);
  u16* Wqg_bf  = (u16*)carve((size_t)BH*2);
  u16* Wqga_bf = (u16*)carve((size_t)BH*2);
  u16* Wqp_bf  = (u16*)carve((size_t)BH*2);
  u16* Wqpa_bf = (u16*)carve((size_t)BH*2);
  u16* Wrg_bf  = (u16*)carve((size_t)BH*2);
  u16* Wrp_bf  = (u16*)carve((size_t)BH*2);
  u16* Wrga_bf = (u16*)carve((size_t)BH*2);
  u16* Wrpa_bf = (u16*)carve((size_t)BH*2);
  u16* xh0     = (u16*)carve((size_t)2*BATCH*1024*2);  // [2][B][x|h] ping
  u16* xh1     = (u16*)carve((size_t)2*BATCH*1024*2);  // pong
  float* c_ws  = (float*)carve((size_t)2*BH*4);
  u16* gl      = (u16*)carve((size_t)2*BH*2);
  float* q_ws  = (float*)carve((size_t)2*KSPQ*BH*4);
  float* q2_ws = (float*)carve((size_t)2*KSPQ*BH*4);
  int*   mask  = (int*)carve((size_t)BS*4);
  float* out   = (float*)d_out;

  init_kernel<<<1024, 256, 0, stream>>>(h0, c0, h0a, c0a, dec, vmask, xh0, c_ws, mask);
  mask_fix_kernel<<<BATCH, 64, 0, stream>>>(mask);

  // --- prologue conversions ---
  const int RB = ((S_LEN*BATCH*HDIM/4)+255)/256;
  remap_kernel<<<RB, 256, 0, stream>>>(ctx, A_ctx);
  remap_kernel<<<RB, 256, 0, stream>>>(dia, A_dia);
  const int NWQ = BH/4;
  f2b_kernel<<<(NWQ+255)/256, 256, 0, stream>>>(Wq_g,  Wqg_bf,  NWQ);
  f2b_kernel<<<(NWQ+255)/256, 256, 0, stream>>>(Wq_ga, Wqga_bf, NWQ);
  f2b_kernel<<<(NWQ+255)/256, 256, 0, stream>>>(Wq_p,  Wqp_bf,  NWQ);
  f2b_kernel<<<(NWQ+255)/256, 256, 0, stream>>>(Wq_pa, Wqpa_bf, NWQ);
  f2b_kernel<<<(NWQ+255)/256, 256, 0, stream>>>(Wr_g,  Wrg_bf,  NWQ);
  f2b_kernel<<<(NWQ+255)/256, 256, 0, stream>>>(Wr_p,  Wrp_bf,  NWQ);
  f2b_kernel<<<(NWQ+255)/256, 256, 0, stream>>>(Wr_ga, Wrga_bf, NWQ);
  f2b_kernel<<<(NWQ+255)/256, 256, 0, stream>>>(Wr_pa, Wrpa_bf, NWQ);
  wperm_kernel<<<(H4*256+255)/256, 256, 0, stream>>>(W_ih,   W_hh,   Wc);
  wperm_kernel<<<(H4*256+255)/256, 256, 0, stream>>>(W_ih_a, W_hh_a, Wc + (size_t)H4*1024);
  bcomb_kernel<<<(2*H4+255)/256, 256, 0, stream>>>(b_ih, b_hh, b_ih_a, b_hh_a, bc);

  // Hoisted context projections -> e (bf16, [B,S,H] row = b*S+s)
  MArgs pa{};
  pa.A[0]=A_ctx; pa.A[1]=A_ctx; pa.A[2]=A_dia; pa.A[3]=A_dia;
  pa.W[0]=Wrg_bf; pa.W[1]=Wrp_bf; pa.W[2]=Wrga_bf; pa.W[3]=Wrpa_bf;
  pa.bias[0]=br_g; pa.bias[1]=br_p; pa.bias[2]=br_ga; pa.bias[3]=br_pa;
  pa.C[0]=e_g; pa.C[1]=e_p; pa.C[2]=e_ga; pa.C[3]=e_pa;
  pa.M=BS; pa.N=HDIM; pa.K=HDIM; pa.lda=HDIM; pa.ksplit=1; pa.out_bf16=1;
  mfma_gemm<<<dim3(4,200,4), 256, 0, stream>>>(pa);

  // emb/ench bf16 copies into the (now dead) A_ctx/A_dia space
  const int NE = S_LEN*BATCH*HDIM/4;
  f2b_kernel<<<(NE+255)/256, 256, 0, stream>>>(emb,  emb_bf,  NE);
  f2b_kernel<<<(NE+255)/256, 256, 0, stream>>>(ench, ench_bf, NE);

  // --- per-step GEMM arg sets ---
  // qg: A = h half of the NEXT xh buffer (written by this step's lstm_gemm)
  MArgs qgE{};   // even t: nxt = xh1
  qgE.A[0]=xh1+512; qgE.A[1]=xh1+(size_t)BATCH*1024+512;
  qgE.W[0]=Wqg_bf; qgE.W[1]=Wqga_bf;
  qgE.bias[0]=qgE.bias[1]=nullptr;
  qgE.C[0]=q_ws; qgE.C[1]=q_ws+(size_t)KSPQ*BH;
  qgE.M=BATCH; qgE.N=HDIM; qgE.K=HDIM; qgE.lda=1024; qgE.ksplit=KSPQ; qgE.out_bf16=0;
  MArgs qgO = qgE;   // odd t: nxt = xh0
  qgO.A[0]=xh0+512; qgO.A[1]=xh0+(size_t)BATCH*1024+512;

  MArgs qp{};
  qp.A[0]=gl; qp.A[1]=gl+BH;
  qp.W[0]=Wqp_bf; qp.W[1]=Wqpa_bf;
  qp.bias[0]=qp.bias[1]=nullptr;
  qp.C[0]=q2_ws; qp.C[1]=q2_ws+(size_t)KSPQ*BH;
  qp.M=BATCH; qp.N=HDIM; qp.K=HDIM; qp.lda=HDIM; qp.ksplit=KSPQ; qp.out_bf16=0;

  for (int t = 0; t < S_LEN; ++t) {
    u16* cur = (t&1) ? xh1 : xh0;
    u16* nxt = (t&1) ? xh0 : xh1;
    lstm_gemm<<<dim3(16,8,2), 256, 0, stream>>>(cur, nxt, Wc, bc, c_ws);
    mfma_gemm<<<dim3(4,4*KSPQ,2), 256, 0, stream>>>((t&1) ? qgO : qgE);
    glimpse_kernel<<<dim3(BATCH,2), 512, 0, stream>>>(q_ws, bq_g, bq_ga, e_g, e_ga, v_g, v_ga, mask, gl);
    mfma_gemm<<<dim3(4,4*KSPQ,2), 256, 0, stream>>>(qp);
    pointer_combine_kernel<<<BATCH, 512, 0, stream>>>(
        q2_ws, bq_p, bq_pa, e_p, e_pa, v_p, v_pa,
        mask, emb_bf, ench_bf, nxt, out, t);
  }
}

// Round 5
// 6178.220 us; speedup vs baseline: 3.5637x; 1.1788x over previous
//
#include <hip/hip_runtime.h>
#include <math.h>

// ---------------------------------------------------------------------------
// Pointer-network decoder, 50 sequential greedy-decode steps.
// R8 == R7 resubmit (round 4 was an infra failure, no measurement).
// R7: revert to the best-measured R3 structure (7 dispatches/step; the R4/R6
// fusion restructures both regressed). Changes vs R3 are ONLY counter-driven:
//  - bf16 GEMM epilogue: LDS-staged coalesced uint4 stores (pa was measured
//    at 820 MB WRITE for a 100 MB output, 8x amp).
//  - fp32 GEMM epilogue: LDS-staged (two 64-row passes) coalesced float4
//    stores (same scattered-store pattern on g_ws/q_ws/q2_ws).
//  - prologue conversion launches batched 14 -> 4.
// R8 delta: fp32 epilogue two-pass loop rewritten as explicit straight-line
// passes (wave-uniform guards, no unrolled loop around __syncthreads).
// ---------------------------------------------------------------------------

#define S_LEN 50
#define BATCH 512
#define HDIM  512
#define H4    2048
#define BH    (BATCH*HDIM)          // 262144
#define BS    (BATCH*S_LEN)         // 25600
#define KSPQ  4                     // split-K for the small q GEMMs
#define MASK50 0x0003FFFFFFFFFFFFULL

typedef unsigned short u16;
typedef __attribute__((ext_vector_type(8))) short bf16x8;
typedef __attribute__((ext_vector_type(4))) float f32x4;

__device__ __forceinline__ float wave_sum(float v){
  #pragma unroll
  for (int o=32;o;o>>=1) v += __shfl_xor(v,o);
  return v;
}
__device__ __forceinline__ float wave_max(float v){
  #pragma unroll
  for (int o=32;o;o>>=1) v = fmaxf(v,__shfl_xor(v,o));
  return v;
}
__device__ __forceinline__ float sigmoidf_(float x){ return 1.0f/(1.0f+expf(-x)); }
__device__ __forceinline__ u16 f2b(float f){
  unsigned u = __float_as_uint(f);
  unsigned r = (u + 0x7fffu + ((u>>16)&1u)) >> 16;
  return (u16)r;
}
__device__ __forceinline__ float b2f(u16 h){ return __uint_as_float(((unsigned)h)<<16); }

// ---------------------------------------------------------------------------
// bf16 MFMA GEMM: C[m,n] = sum_k A[m,k]*W[n,k] (+bias[n]).
// A rows at stride lda, W row-major [N,K]. 128x128 tile, BK=64, 256 thr =
// 4 waves (2x2 of 64x64), each wave 4x4 MFMA tiles. M mult of 128.
// ksplit: blockIdx.y = mtile*ksplit+ksp; fp32 partial at C + ksp*M*N.
// Both epilogues LDS-staged -> fully coalesced wide stores (write-amp fix).
// ---------------------------------------------------------------------------
struct MArgs {
  const u16* A[4]; const u16* W[4]; const float* bias[4]; void* C[4];
  int M, N, K, lda, ksplit, out_bf16;
};

__global__ __launch_bounds__(256, 2) void mfma_gemm(MArgs g) {
  const int z = blockIdx.z;
  const u16* __restrict__ A = g.A[z];
  const u16* __restrict__ W = g.W[z];
  const float* __restrict__ bias = g.bias[z];
  const int N = g.N, K = g.K, lda = g.lda;
  const int mtile = blockIdx.y / g.ksplit;
  const int ksp   = blockIdx.y % g.ksplit;
  const int m0 = mtile*128, n0 = blockIdx.x*128;
  const int kc = K / g.ksplit;
  const int kbeg = ksp*kc, kend = kbeg+kc;

  // row stride 88 bf16 = 176 B: 16B-aligned, 2-way-max bank aliasing on b128
  __shared__ __align__(16) u16 sh[2*128*88];   // 45056 B
  u16* As = sh;
  u16* Bs = sh + 128*88;

  const int tid = threadIdx.x;
  const int wave = tid>>6, lane = tid&63;
  const int wm = (wave>>1)*64, wn = (wave&1)*64;
  const int m16 = lane&15, quad = lane>>4;

  f32x4 acc[4][4];
  #pragma unroll
  for (int i=0;i<4;i++)
    #pragma unroll
    for (int j=0;j<4;j++) acc[i][j] = (f32x4){0.f,0.f,0.f,0.f};

  for (int kt = kbeg; kt < kend; kt += 64) {
    uint4 av[4], wv[4];
    #pragma unroll
    for (int it=0; it<4; it++){
      int idx = tid + it*256;
      int r = idx>>3, c = idx&7;
      av[it] = *(const uint4*)(A + (size_t)(m0+r)*lda + kt + c*8);
      wv[it] = *(const uint4*)(W + (size_t)(n0+r)*K + kt + c*8);
    }
    __syncthreads();
    #pragma unroll
    for (int it=0; it<4; it++){
      int idx = tid + it*256;
      int r = idx>>3, c = idx&7;
      *(uint4*)&As[r*88 + c*8] = av[it];
      *(uint4*)&Bs[r*88 + c*8] = wv[it];
    }
    __syncthreads();
    #pragma unroll
    for (int ks=0; ks<2; ks++){
      bf16x8 af[4], bfr[4];
      #pragma unroll
      for (int i=0;i<4;i++) af[i] = *(const bf16x8*)&As[(wm + i*16 + m16)*88 + ks*32 + quad*8];
      #pragma unroll
      for (int j=0;j<4;j++) bfr[j] = *(const bf16x8*)&Bs[(wn + j*16 + m16)*88 + ks*32 + quad*8];
      #pragma unroll
      for (int i=0;i<4;i++)
        #pragma unroll
        for (int j=0;j<4;j++)
          acc[i][j] = __builtin_amdgcn_mfma_f32_16x16x32_bf16(af[i], bfr[j], acc[i][j], 0, 0, 0);
    }
  }

  if (g.out_bf16) {
    // stage bf16 tile (bias added) in LDS, then write coalesced uint4 rows
    u16* C = (u16*)g.C[z];
    __syncthreads();
    #pragma unroll
    for (int i=0;i<4;i++){
      #pragma unroll
      for (int j=0;j<4;j++){
        int cc = wn + j*16 + m16;
        float bv = bias ? bias[n0 + cc] : 0.0f;
        #pragma unroll
        for (int r=0;r<4;r++)
          sh[(wm + i*16 + quad*4 + r)*128 + cc] = f2b(acc[i][j][r] + bv);
      }
    }
    __syncthreads();
    #pragma unroll
    for (int k=0;k<8;k++){
      int idx = tid + k*256;
      int row = idx>>4, c = idx&15;
      *(uint4*)(C + (size_t)(m0+row)*N + n0 + c*8) = *(const uint4*)&sh[row*128 + c*8];
    }
  } else {
    // fp32: stage 64 rows at a time (64x128 fp32 = 32 KB fits in the 44 KB
    // LDS block), store coalesced float4. Wave-uniform guards; straight-line.
    float* C = (float*)g.C[z] + (size_t)ksp*g.M*N;
    float* shf = (float*)sh;
    // pass 0: rows 0..63 (waves 0,1 own them: wm==0)
    __syncthreads();
    if (wm == 0){
      #pragma unroll
      for (int i=0;i<4;i++){
        int mb = i*16 + quad*4;
        #pragma unroll
        for (int j=0;j<4;j++){
          int cc = wn + j*16 + m16;
          float bv = bias ? bias[n0 + cc] : 0.0f;
          #pragma unroll
          for (int r=0;r<4;r++) shf[(mb+r)*128 + cc] = acc[i][j][r] + bv;
        }
      }
    }
    __syncthreads();
    #pragma unroll
    for (int k=0;k<8;k++){
      int idx = tid + k*256;
      int row = idx>>5, c = idx&31;
      *(float4*)(C + (size_t)(m0 + row)*N + n0 + c*4) = *(const float4*)&shf[row*128 + c*4];
    }
    // pass 1: rows 64..127 (waves 2,3: wm==64)
    __syncthreads();
    if (wm == 64){
      #pragma unroll
      for (int i=0;i<4;i++){
        int mb = i*16 + quad*4;
        #pragma unroll
        for (int j=0;j<4;j++){
          int cc = wn + j*16 + m16;
          float bv = bias ? bias[n0 + cc] : 0.0f;
          #pragma unroll
          for (int r=0;r<4;r++) shf[(mb+r)*128 + cc] = acc[i][j][r] + bv;
        }
      }
    }
    __syncthreads();
    #pragma unroll
    for (int k=0;k<8;k++){
      int idx = tid + k*256;
      int row = idx>>5, c = idx&31;
      *(float4*)(C + (size_t)(m0 + 64 + row)*N + n0 + c*4) = *(const float4*)&shf[row*128 + c*4];
    }
  }
}

// ---------------------------------------------------------------------------
// Batched fp32 -> bf16 conversions (job per blockIdx.y)
// ---------------------------------------------------------------------------
struct F2BJobs { const float* s[8]; u16* d[8]; int n4; };

__global__ void f2b_multi(F2BJobs J){
  const float* __restrict__ src = J.s[blockIdx.y];
  u16* __restrict__ dst = J.d[blockIdx.y];
  int i = blockIdx.x*blockDim.x + threadIdx.x;
  if (i >= J.n4) return;
  float4 v = *(const float4*)(src + (size_t)i*4);
  ushort4 o; o.x=f2b(v.x); o.y=f2b(v.y); o.z=f2b(v.z); o.w=f2b(v.w);
  *(ushort4*)(dst + (size_t)i*4) = o;
}

// [S,B,H] fp32 -> [(b*S+s),H] bf16 (proj-GEMM A layout); blockIdx.y picks job
__global__ void remap2_kernel(const float* __restrict__ srcA, u16* __restrict__ dstA,
                              const float* __restrict__ srcB, u16* __restrict__ dstB){
  const float* __restrict__ src = blockIdx.y ? srcB : srcA;
  u16* __restrict__ dst = blockIdx.y ? dstB : dstA;
  int i = blockIdx.x*blockDim.x + threadIdx.x;     // over S*B*H/4
  if (i >= (S_LEN*BATCH*HDIM)/4) return;
  int elem = i*4;
  int s = elem >> 18;            // /(B*H)
  int b = (elem >> 9) & 511;
  int h = elem & 511;
  float4 v = *(const float4*)(src + (size_t)s*BATCH*HDIM + (size_t)b*HDIM + h);
  ushort4 o; o.x=f2b(v.x); o.y=f2b(v.y); o.z=f2b(v.z); o.w=f2b(v.w);
  *(ushort4*)(dst + ((size_t)b*S_LEN + s)*HDIM + h) = o;
}

// ---------------------------------------------------------------------------
// init: states + decoder inputs (bf16 activations, fp32 c), mask
// ---------------------------------------------------------------------------
__global__ void init_kernel(const float* __restrict__ h0, const float* __restrict__ c0,
                            const float* __restrict__ h0a, const float* __restrict__ c0a,
                            const float* __restrict__ dec, const unsigned char* __restrict__ vmask,
                            u16* __restrict__ h_bf, float* __restrict__ c_ws,
                            u16* __restrict__ x_bf, u16* __restrict__ xa_bf,
                            int* __restrict__ mask){
  for (int i = blockIdx.x*blockDim.x + threadIdx.x; i < BH; i += gridDim.x*blockDim.x) {
    h_bf[i]=f2b(h0[i]); h_bf[BH+i]=f2b(h0a[i]);
    c_ws[i]=c0[i];      c_ws[BH+i]=c0a[i];
    u16 d = f2b(dec[i]);
    x_bf[i]=d; xa_bf[i]=d;
    if (i < BS) mask[i] = vmask[i] ? 1 : 0;
  }
}

__global__ __launch_bounds__(64) void mask_fix_kernel(int* __restrict__ mask){
  int b = blockIdx.x, lane = threadIdx.x;
  int mv = (lane < S_LEN) ? mask[b*S_LEN+lane] : 1;
  unsigned long long bal = __ballot(mv != 0);
  if ((bal & MASK50) == MASK50 && lane == 49) mask[b*S_LEN+49] = 0;
}

// ---------------------------------------------------------------------------
// LSTM gate nonlinearity. g_ws: [0]=x*Wih^T [1]=h*Whh^T (main), [2],[3] aoi.
// Writes h as bf16 (GEMM operand), c as fp32.
// ---------------------------------------------------------------------------
__global__ void gates_kernel(const float* __restrict__ g_ws,
                             const float* __restrict__ b_ih, const float* __restrict__ b_hh,
                             const float* __restrict__ b_ih_a, const float* __restrict__ b_hh_a,
                             u16* __restrict__ h_bf, float* __restrict__ c_ws){
  int i = blockIdx.x*blockDim.x + threadIdx.x;          // over 2*BH
  if (i >= 2*BH) return;
  int z = i / BH, r = i % BH;
  int b = r >> 9, j = r & 511;
  const float* gA = g_ws + (size_t)(2*z+0)*BATCH*H4 + (size_t)b*H4;
  const float* gB = g_ws + (size_t)(2*z+1)*BATCH*H4 + (size_t)b*H4;
  const float* bi = z ? b_ih_a : b_ih;
  const float* bh = z ? b_hh_a : b_hh;
  float gi = gA[j]      + gB[j]      + bi[j]      + bh[j];
  float gf = gA[512+j]  + gB[512+j]  + bi[512+j]  + bh[512+j];
  float gg = gA[1024+j] + gB[1024+j] + bi[1024+j] + bh[1024+j];
  float go = gA[1536+j] + gB[1536+j] + bi[1536+j] + bh[1536+j];
  float cp = c_ws[i];
  float c2 = sigmoidf_(gf)*cp + sigmoidf_(gi)*tanhf(gg);
  float h2 = sigmoidf_(go)*tanhf(c2);
  c_ws[i] = c2; h_bf[i] = f2b(h2);
}

// ---------------------------------------------------------------------------
// Glimpse attention on bf16 e [B,S,H]: logits+mask+softmax+weighted sum.
// q = sum of KSPQ fp32 partials + bq, held in registers (8 contig h per lane).
// ---------------------------------------------------------------------------
__global__ __launch_bounds__(512) void glimpse_kernel(
    const float* __restrict__ qpart,
    const float* __restrict__ bq_g, const float* __restrict__ bq_ga,
    const u16* __restrict__ e_g, const u16* __restrict__ e_ga,
    const float* __restrict__ v_g, const float* __restrict__ v_ga,
    const int* __restrict__ mask, u16* __restrict__ gl_ws){
  int z = blockIdx.y, b = blockIdx.x, tid = threadIdx.x;
  const u16* e = (z ? e_ga : e_g) + (size_t)b*S_LEN*HDIM;
  const float* v  = z ? v_ga : v_g;
  const float* bq = z ? bq_ga : bq_g;
  const float* qp = qpart + (size_t)z*KSPQ*BH + (size_t)b*HDIM;
  __shared__ float lg_sh[64], p_sh[64];
  int w = tid>>6, lane = tid&63;
  int h0 = lane*8;
  float qreg[8], vreg[8];
  #pragma unroll
  for (int ii=0; ii<8; ii++){
    int h = h0+ii;
    float q = bq[h];
    #pragma unroll
    for (int p=0;p<KSPQ;p++) q += qp[(size_t)p*BH + h];
    qreg[ii]=q; vreg[ii]=v[h];
  }
  for (int s = w; s < S_LEN; s += 8) {
    uint4 ev = *(const uint4*)(e + (size_t)s*HDIM + h0);
    const u16* pe = (const u16*)&ev;
    float acc = 0.0f;
    #pragma unroll
    for (int ii=0; ii<8; ii++) acc += vreg[ii]*tanhf(qreg[ii] + b2f(pe[ii]));
    acc = wave_sum(acc);
    if (lane==0) lg_sh[s] = mask[b*S_LEN+s] ? -INFINITY : acc;
  }
  __syncthreads();
  if (tid < 64) {
    float val = (tid < S_LEN) ? lg_sh[tid] : -INFINITY;
    float mx = wave_max(val);
    float ex = (tid < S_LEN) ? expf(val - mx) : 0.0f;
    float sm = wave_sum(ex);
    if (tid < S_LEN) p_sh[tid] = ex / sm;
  }
  __syncthreads();
  float acc = 0.0f;
  for (int s=0;s<S_LEN;s++) acc += p_sh[s]*b2f(e[(size_t)s*HDIM + tid]);
  gl_ws[(size_t)z*BH + (size_t)b*HDIM + tid] = f2b(acc);
}

// ---------------------------------------------------------------------------
// Pointer attention: lp[s] = mask ? -inf : 10*tanh(sum_h v*tanh(q+e))
// ---------------------------------------------------------------------------
__global__ __launch_bounds__(512) void pointer_kernel(
    const float* __restrict__ qpart,
    const float* __restrict__ bq_p, const float* __restrict__ bq_pa,
    const u16* __restrict__ e_p, const u16* __restrict__ e_pa,
    const float* __restrict__ v_p, const float* __restrict__ v_pa,
    const int* __restrict__ mask, float* __restrict__ lp_ws){
  int z = blockIdx.y, b = blockIdx.x, tid = threadIdx.x;
  const u16* e = (z ? e_pa : e_p) + (size_t)b*S_LEN*HDIM;
  const float* v  = z ? v_pa : v_p;
  const float* bq = z ? bq_pa : bq_p;
  const float* qp = qpart + (size_t)z*KSPQ*BH + (size_t)b*HDIM;
  int w = tid>>6, lane = tid&63;
  int h0 = lane*8;
  float qreg[8], vreg[8];
  #pragma unroll
  for (int ii=0; ii<8; ii++){
    int h = h0+ii;
    float q = bq[h];
    #pragma unroll
    for (int p=0;p<KSPQ;p++) q += qp[(size_t)p*BH + h];
    qreg[ii]=q; vreg[ii]=v[h];
  }
  for (int s = w; s < S_LEN; s += 8) {
    uint4 ev = *(const uint4*)(e + (size_t)s*HDIM + h0);
    const u16* pe = (const u16*)&ev;
    float acc = 0.0f;
    #pragma unroll
    for (int ii=0; ii<8; ii++) acc += vreg[ii]*tanhf(qreg[ii] + b2f(pe[ii]));
    acc = wave_sum(acc);
    if (lane==0) lp_ws[(size_t)z*BS + b*S_LEN + s] = mask[b*S_LEN+s] ? -INFINITY : 10.0f*tanhf(acc);
  }
}

// ---------------------------------------------------------------------------
// Combine: log_softmax(lp)+0.1*log_softmax(lpa), argmax, gather, mask update.
// Output write clamps -inf -> -1e30 (harness absmax NaNs on inf-inf).
// ---------------------------------------------------------------------------
__global__ __launch_bounds__(64) void combine_kernel(
    const float* __restrict__ lp_ws, float* __restrict__ out, int t,
    const u16* __restrict__ emb_bf, const u16* __restrict__ ench_bf,
    u16* __restrict__ x_bf, u16* __restrict__ xa_bf, int* __restrict__ mask){
  int b = blockIdx.x, lane = threadIdx.x;
  float a  = (lane < S_LEN) ? lp_ws[b*S_LEN + lane]       : -INFINITY;
  float ca = (lane < S_LEN) ? lp_ws[BS + b*S_LEN + lane]  : -INFINITY;
  float m1 = wave_max(a);
  float l1 = logf(wave_sum((lane < S_LEN) ? expf(a - m1) : 0.0f));
  float m2 = wave_max(ca);
  float l2 = logf(wave_sum((lane < S_LEN) ? expf(ca - m2) : 0.0f));
  float logp = (a - m1 - l1) + 0.1f * (ca - m2 - l2);
  if (lane < S_LEN) out[(size_t)b*(S_LEN*S_LEN) + t*S_LEN + lane] = fmaxf(logp, -1e30f);
  float v = (lane < S_LEN) ? logp : -INFINITY;
  int bi = lane;
  #pragma unroll
  for (int o=32;o;o>>=1) {
    float ov = __shfl_xor(v, o); int oi = __shfl_xor(bi, o);
    if (ov > v || (ov == v && oi < bi)) { v = ov; bi = oi; }
  }
  int idx = bi;
  if (lane == 0) out[(size_t)BATCH*S_LEN*S_LEN + b*S_LEN + t] = (float)idx;
  const u16* esrc = emb_bf  + ((size_t)idx*BATCH + b)*HDIM;
  const u16* asrc = ench_bf + ((size_t)idx*BATCH + b)*HDIM;
  u16* xdst = x_bf  + (size_t)b*HDIM;
  u16* adst = xa_bf + (size_t)b*HDIM;
  for (int e0 = lane; e0 < HDIM; e0 += 64) { xdst[e0] = esrc[e0]; adst[e0] = asrc[e0]; }
  int mv = 1;
  if (lane < S_LEN) { mv = mask[b*S_LEN+lane]; if (lane==idx) mv = 1; mask[b*S_LEN+lane] = mv; }
  unsigned long long bal = __ballot(mv != 0);
  if ((bal & MASK50) == MASK50 && lane == 49) mask[b*S_LEN+49] = 0;
}

// ---------------------------------------------------------------------------
extern "C" void kernel_launch(void* const* d_in, const int* in_sizes, int n_in,
                              void* d_out, int out_size, void* d_ws, size_t ws_size,
                              hipStream_t stream) {
  (void)in_sizes; (void)n_in; (void)out_size; (void)ws_size;
  const float* dec    = (const float*)d_in[0];
  const float* emb    = (const float*)d_in[1];
  const float* h0     = (const float*)d_in[2];
  const float* c0     = (const float*)d_in[3];
  const float* ctx    = (const float*)d_in[4];
  const float* ench   = (const float*)d_in[5];
  const float* dia    = (const float*)d_in[6];
  const float* h0a    = (const float*)d_in[7];
  const float* c0a    = (const float*)d_in[8];
  const unsigned char* vmask = (const unsigned char*)d_in[9];
  const float* W_ih   = (const float*)d_in[10];
  const float* W_hh   = (const float*)d_in[11];
  const float* b_ih   = (const float*)d_in[12];
  const float* b_hh   = (const float*)d_in[13];
  const float* W_ih_a = (const float*)d_in[14];
  const float* W_hh_a = (const float*)d_in[15];
  const float* b_ih_a = (const float*)d_in[16];
  const float* b_hh_a = (const float*)d_in[17];
  const float* Wq_p  = (const float*)d_in[18];
  const float* bq_p  = (const float*)d_in[19];
  const float* Wr_p  = (const float*)d_in[20];
  const float* br_p  = (const float*)d_in[21];
  const float* v_p   = (const float*)d_in[22];
  const float* Wq_pa = (const float*)d_in[23];
  const float* bq_pa = (const float*)d_in[24];
  const float* Wr_pa = (const float*)d_in[25];
  const float* br_pa = (const float*)d_in[26];
  const float* v_pa  = (const float*)d_in[27];
  const float* Wq_g  = (const float*)d_in[28];
  const float* bq_g  = (const float*)d_in[29];
  const float* Wr_g  = (const float*)d_in[30];
  const float* br_g  = (const float*)d_in[31];
  const float* v_g   = (const float*)d_in[32];
  const float* Wq_ga = (const float*)d_in[33];
  const float* bq_ga = (const float*)d_in[34];
  const float* Wr_ga = (const float*)d_in[35];
  const float* br_ga = (const float*)d_in[36];
  const float* v_ga  = (const float*)d_in[37];

  char* base = (char*)d_ws;
  size_t off = 0;
  auto carve = [&](size_t bytes)->char*{ char* p = base + off; off += (bytes + 255) & ~(size_t)255; return p; };

  const size_t E_BYTES = (size_t)BS*HDIM*2;      // 26,214,400
  u16* e_g   = (u16*)carve(E_BYTES);
  u16* e_p   = (u16*)carve(E_BYTES);
  u16* e_ga  = (u16*)carve(E_BYTES);
  u16* e_pa  = (u16*)carve(E_BYTES);
  char* scratch = carve(2*E_BYTES);              // A_ctx/A_dia, later emb/ench bf16
  u16* A_ctx  = (u16*)scratch;
  u16* A_dia  = (u16*)(scratch + E_BYTES);
  u16* emb_bf  = A_ctx;                          // aliases (prologue-ordered)
  u16* ench_bf = A_dia;
  u16* Wih_bf  = (u16*)carve((size_t)H4*HDIM*2);
  u16* Whh_bf  = (u16*)carve((size_t)H4*HDIM*2);
  u16* Wiha_bf = (u16*)carve((size_t)H4*HDIM*2);
  u16* Whha_bf = (u16*)carve((size_t)H4*HDIM*2);
  u16* Wqg_bf  = (u16*)carve((size_t)BH*2);      // 512x512
  u16* Wqga_bf = (u16*)carve((size_t)BH*2);
  u16* Wqp_bf  = (u16*)carve((size_t)BH*2);
  u16* Wqpa_bf = (u16*)carve((size_t)BH*2);
  u16* Wrg_bf  = (u16*)carve((size_t)BH*2);
  u16* Wrp_bf  = (u16*)carve((size_t)BH*2);
  u16* Wrga_bf = (u16*)carve((size_t)BH*2);
  u16* Wrpa_bf = (u16*)carve((size_t)BH*2);
  u16* x_bf    = (u16*)carve((size_t)BH*2);
  u16* xa_bf   = (u16*)carve((size_t)BH*2);
  u16* h_bf    = (u16*)carve((size_t)2*BH*2);    // [2][B][H]
  float* c_ws  = (float*)carve((size_t)2*BH*4);
  float* g_ws  = (float*)carve((size_t)4*BATCH*H4*4);
  u16* gl      = (u16*)carve((size_t)2*BH*2);
  float* q_ws  = (float*)carve((size_t)2*KSPQ*BH*4);
  float* q2_ws = (float*)carve((size_t)2*KSPQ*BH*4);
  float* lp_ws = (float*)carve((size_t)2*BS*4);
  int*   mask  = (int*)carve((size_t)BS*4);
  float* out   = (float*)d_out;

  init_kernel<<<1024, 256, 0, stream>>>(h0, c0, h0a, c0a, dec, vmask,
                                        h_bf, c_ws, x_bf, xa_bf, mask);
  mask_fix_kernel<<<BATCH, 64, 0, stream>>>(mask);

  // --- prologue conversions (batched) ---
  const int RB = ((S_LEN*BATCH*HDIM/4)+255)/256;
  remap2_kernel<<<dim3(RB,2), 256, 0, stream>>>(ctx, A_ctx, dia, A_dia);

  const int NW4 = H4*HDIM/4, NWQ = BH/4;
  F2BJobs jw{};   // 4 LSTM weight matrices [2048x512]
  jw.s[0]=W_ih; jw.d[0]=Wih_bf;  jw.s[1]=W_hh; jw.d[1]=Whh_bf;
  jw.s[2]=W_ih_a; jw.d[2]=Wiha_bf; jw.s[3]=W_hh_a; jw.d[3]=Whha_bf;
  jw.n4 = NW4;
  f2b_multi<<<dim3((NW4+255)/256,4), 256, 0, stream>>>(jw);

  F2BJobs jq{};   // 8 attention weight matrices [512x512]
  jq.s[0]=Wq_g;  jq.d[0]=Wqg_bf;  jq.s[1]=Wq_ga; jq.d[1]=Wqga_bf;
  jq.s[2]=Wq_p;  jq.d[2]=Wqp_bf;  jq.s[3]=Wq_pa; jq.d[3]=Wqpa_bf;
  jq.s[4]=Wr_g;  jq.d[4]=Wrg_bf;  jq.s[5]=Wr_p;  jq.d[5]=Wrp_bf;
  jq.s[6]=Wr_ga; jq.d[6]=Wrga_bf; jq.s[7]=Wr_pa; jq.d[7]=Wrpa_bf;
  jq.n4 = NWQ;
  f2b_multi<<<dim3((NWQ+255)/256,8), 256, 0, stream>>>(jq);

  // Hoisted context projections -> e (bf16, [B,S,H] row = b*S+s)
  MArgs pa{};
  pa.A[0]=A_ctx; pa.A[1]=A_ctx; pa.A[2]=A_dia; pa.A[3]=A_dia;
  pa.W[0]=Wrg_bf; pa.W[1]=Wrp_bf; pa.W[2]=Wrga_bf; pa.W[3]=Wrpa_bf;
  pa.bias[0]=br_g; pa.bias[1]=br_p; pa.bias[2]=br_ga; pa.bias[3]=br_pa;
  pa.C[0]=e_g; pa.C[1]=e_p; pa.C[2]=e_ga; pa.C[3]=e_pa;
  pa.M=BS; pa.N=HDIM; pa.K=HDIM; pa.lda=HDIM; pa.ksplit=1; pa.out_bf16=1;
  mfma_gemm<<<dim3(4,200,4), 256, 0, stream>>>(pa);

  // emb/ench bf16 copies into the (now dead) A_ctx/A_dia space
  const int NE = S_LEN*BATCH*HDIM/4;
  F2BJobs je{};
  je.s[0]=emb; je.d[0]=emb_bf; je.s[1]=ench; je.d[1]=ench_bf;
  je.n4 = NE;
  f2b_multi<<<dim3((NE+255)/256,2), 256, 0, stream>>>(je);

  // --- per-step GEMM arg sets ---
  MArgs la{};
  la.A[0]=x_bf; la.A[1]=h_bf; la.A[2]=xa_bf; la.A[3]=h_bf+BH;
  la.W[0]=Wih_bf; la.W[1]=Whh_bf; la.W[2]=Wiha_bf; la.W[3]=Whha_bf;
  la.bias[0]=la.bias[1]=la.bias[2]=la.bias[3]=nullptr;
  la.C[0]=g_ws; la.C[1]=g_ws+(size_t)BATCH*H4; la.C[2]=g_ws+2*(size_t)BATCH*H4; la.C[3]=g_ws+3*(size_t)BATCH*H4;
  la.M=BATCH; la.N=H4; la.K=HDIM; la.lda=HDIM; la.ksplit=1; la.out_bf16=0;

  MArgs qg{};
  qg.A[0]=h_bf; qg.A[1]=h_bf+BH;
  qg.W[0]=Wqg_bf; qg.W[1]=Wqga_bf;
  qg.bias[0]=qg.bias[1]=qg.bias[2]=qg.bias[3]=nullptr;
  qg.C[0]=q_ws; qg.C[1]=q_ws+(size_t)KSPQ*BH;
  qg.M=BATCH; qg.N=HDIM; qg.K=HDIM; qg.lda=HDIM; qg.ksplit=KSPQ; qg.out_bf16=0;

  MArgs qp{};
  qp.A[0]=gl; qp.A[1]=gl+BH;
  qp.W[0]=Wqp_bf; qp.W[1]=Wqpa_bf;
  qp.bias[0]=qp.bias[1]=qp.bias[2]=qp.bias[3]=nullptr;
  qp.C[0]=q2_ws; qp.C[1]=q2_ws+(size_t)KSPQ*BH;
  qp.M=BATCH; qp.N=HDIM; qp.K=HDIM; qp.lda=HDIM; qp.ksplit=KSPQ; qp.out_bf16=0;

  for (int t = 0; t < S_LEN; ++t) {
    mfma_gemm<<<dim3(16,4,4), 256, 0, stream>>>(la);
    gates_kernel<<<(2*BH+255)/256, 256, 0, stream>>>(g_ws, b_ih, b_hh, b_ih_a, b_hh_a, h_bf, c_ws);
    mfma_gemm<<<dim3(4,4*KSPQ,2), 256, 0, stream>>>(qg);
    glimpse_kernel<<<dim3(BATCH,2), 512, 0, stream>>>(q_ws, bq_g, bq_ga, e_g, e_ga, v_g, v_ga, mask, gl);
    mfma_gemm<<<dim3(4,4*KSPQ,2), 256, 0, stream>>>(qp);
    pointer_kernel<<<dim3(BATCH,2), 512, 0, stream>>>(q2_ws, bq_p, bq_pa, e_p, e_pa, v_p, v_pa, mask, lp_ws);
    combine_kernel<<<BATCH, 64, 0, stream>>>(lp_ws, out, t, emb_bf, ench_bf, x_bf, xa_bf, mask);
  }
}